// Round 11
// baseline (1615.855 us; speedup 1.0000x reference)
//
#include <hip/hip_runtime.h>
#include <cstdint>

#define L_LAYERS 6

typedef __attribute__((ext_vector_type(8))) short bf16x8;
typedef __attribute__((ext_vector_type(4))) float f32x4;
typedef __attribute__((ext_vector_type(2))) float f32x2;

__device__ __forceinline__ float gelu1(float v) {
    return 0.5f * v * (1.0f + erff(v * 0.7071067811865475f));
}

__device__ __forceinline__ unsigned int f2bf2(float a, float b) {
    union { float f; unsigned u; } x, y;
    x.f = a; y.f = b;
    unsigned lo = (x.u + 0x7FFFu + ((x.u >> 16) & 1u)) >> 16;
    unsigned hi = (y.u + 0x7FFFu + ((y.u >> 16) & 1u)) & 0xFFFF0000u;
    return lo | hi;
}

__device__ __forceinline__ unsigned short f2bf1(float a) {
    union { float f; unsigned u; } x;
    x.f = a;
    return (unsigned short)((x.u + 0x7FFFu + ((x.u >> 16) & 1u)) >> 16);
}

// single-instruction RNE pack of two f32 -> packed bf16x2 (same rounding as f2bf2)
__device__ __forceinline__ unsigned cvt_pk_bf16(float lo, float hi) {
    unsigned r;
    asm("v_cvt_pk_bf16_f32 %0, %1, %2" : "=v"(r) : "v"(lo), "v"(hi));
    return r;
}

__device__ __forceinline__ float2 bfp2(unsigned u) {
    union { unsigned u; float f; } a, b;
    a.u = u << 16;
    b.u = u & 0xFFFF0000u;
    return make_float2(a.f, b.f);
}

// async global->LDS, 16 bytes per lane (dest = wave-uniform base + lane*16)
__device__ __forceinline__ void gload16(const void* g, void* l) {
    __builtin_amdgcn_global_load_lds(
        (const __attribute__((address_space(1))) void*)g,
        (__attribute__((address_space(3))) void*)l, 16, 0, 0);
}

// ---------------- utility ----------------

__global__ void k_zero(int* __restrict__ p, int n) {
    int i = blockIdx.x * 256 + threadIdx.x;
    if (i < n) p[i] = 0;
}

// f32 -> bf16 bulk convert (8 elems/thread, fully vectorized; G13)
__global__ void k_cvt(const float* __restrict__ x, short* __restrict__ xb, int n8) {
    int i = blockIdx.x * 256 + threadIdx.x;
    if (i < n8) {
        const float4* p = (const float4*)(x + (size_t)i * 8);
        float4 a0 = p[0], a1 = p[1];
        uint4 o;
        o.x = f2bf2(a0.x, a0.y);
        o.y = f2bf2(a0.z, a0.w);
        o.z = f2bf2(a1.x, a1.y);
        o.w = f2bf2(a1.z, a1.w);
        *(uint4*)(xb + (size_t)i * 8) = o;
    }
}

// ---------------- edge sorting (counting sort by dst) ----------------

__global__ void k_hist(const int* __restrict__ dst, int* __restrict__ hist, int E) {
    int e = blockIdx.x * 256 + threadIdx.x;
    if (e < E) atomicAdd(&hist[dst[e]], 1);
}

__global__ __launch_bounds__(1024) void k_scan(const int* __restrict__ hist,
                                               int* __restrict__ off, int n) {
    __shared__ int buf[1024];
    __shared__ int carry;
    int tid = threadIdx.x;
    if (tid == 0) carry = 0;
    __syncthreads();
    for (int base = 0; base < n; base += 1024) {
        int v = (base + tid < n) ? hist[base + tid] : 0;
        buf[tid] = v;
        __syncthreads();
        int x = v;
        for (int o = 1; o < 1024; o <<= 1) {
            int t = (tid >= o) ? buf[tid - o] : 0;
            __syncthreads();
            x += t;
            buf[tid] = x;
            __syncthreads();
        }
        int c = carry;
        if (base + tid < n) off[base + tid] = c + x - v;   // exclusive
        __syncthreads();
        if (tid == 1023) carry = c + buf[1023];
        __syncthreads();
    }
    if (tid == 0) off[n] = carry;
}

__global__ void k_scatter(const int* __restrict__ src, const int* __restrict__ dst,
                          const int* __restrict__ off, int* __restrict__ cursor,
                          int* __restrict__ srcS, int E) {
    int e = blockIdx.x * 256 + threadIdx.x;
    if (e < E) {
        int d = dst[e];
        int pos = off[d] + atomicAdd(&cursor[d], 1);
        srcS[pos] = src[e];
    }
}

// ---------------- weight prep (transpose + cvt to bf16) ----------------

__global__ void k_wcat(const float* __restrict__ Wq, const float* __restrict__ Wk,
                       const float* __restrict__ Wv, const float* __restrict__ Ws,
                       short* __restrict__ Wt) {
    int idx = blockIdx.x * 256 + threadIdx.x;   // l*2^20 + n*512 + k
    int k = idx & 511;
    int nf = (idx >> 9) & 2047;
    int l = idx >> 20;
    int sel = nf >> 9, nn = nf & 511;
    const float* W = (sel == 0) ? Wq : (sel == 1) ? Wk : (sel == 2) ? Wv : Ws;
    float v = W[((size_t)l * 512 + k) * 512 + nn];
    Wt[idx] = (short)f2bf1(v);
}

// swz=1: XOR-permute 16B sub-blocks within each 64B k-chunk by ((n>>1)&3) so that
// linear global_load_lds staging + swizzled ds_read in gemm_gate is conflict-free.
__global__ void k_tr(const float* __restrict__ W, short* __restrict__ Wt, int K, int N,
                     int swz) {
    int k = blockIdx.x * 256 + threadIdx.x;
    int n = blockIdx.y;
    if (k < K) {
        int kk = k;
        if (swz) kk = (k & ~31) | (((((k >> 3) & 3) ^ ((n >> 1) & 3))) << 3) | (k & 7);
        Wt[(size_t)n * K + kk] = (short)f2bf1(W[(size_t)k * N + n]);
    }
}

__global__ void k_bcat(const float* __restrict__ bq, const float* __restrict__ bk,
                       const float* __restrict__ bv, const float* __restrict__ bs,
                       float* __restrict__ bcat) {
    int idx = blockIdx.x * 256 + threadIdx.x;
    if (idx >= L_LAYERS * 2048) return;
    int l = idx >> 11, n = idx & 2047;
    int sel = n >> 9, nn = n & 511;
    const float* b = (sel == 0) ? bq : (sel == 1) ? bk : (sel == 2) ? bv : bs;
    bcat[idx] = b[l * 512 + nn];
}

__global__ void k_bdual(const float* __restrict__ sb, const float* __restrict__ ab,
                        float* __restrict__ bd) {
    int idx = blockIdx.x * 256 + threadIdx.x;
    if (idx < 1024) bd[idx] = (idx < 512) ? sb[idx] : ab[idx - 512];
}

// ---------------- GEMM: A bf16, B bf16, 3-buffer 2-deep pipelined staging -------------
// Stage k+2 issued right after barrier k (2 compute iterations of cover), counted
// vmcnt(4) at top retires exactly stage k. NO setprio (m190/R6). Tail peeled.
// Requires K >= 96 (>=3 steps); call sites use K=512/768.
// Optional outputs: C8 (fp8 e4m3 copy), Cf (f32 copy, for the mixer's residual h).
// asel=1: block-diagonal mode for the merged bilinear GEMM — A column base is
// (col0 & 512), so C[:,0:512] = A[:,0:512]@Bt[0:512] and C[:,512:] = A[:,512:]@Bt[512:].

__global__ __launch_bounds__(256) void gemm_bb(
    const short* __restrict__ A, int lda,
    const short* __restrict__ Bt,
    const float* __restrict__ bias,
    short* __restrict__ C, unsigned char* __restrict__ C8, float* __restrict__ Cf,
    int ldc, int M, int N, int K, int act, int asel) {
    __shared__ __align__(16) short As[3 * 128 * 32];   // 24 KB
    __shared__ __align__(16) short Bs[3 * 128 * 32];   // 24 KB
    const int tid = threadIdx.x;
    const int lane = tid & 63;
    const int wave = tid >> 6;
    const int wr = (wave >> 1) * 64;
    const int wc = (wave & 1) * 64;
    const int l16 = lane & 15;
    const int quad = lane >> 4;
    const int row0 = blockIdx.x * 128;
    const int col0 = blockIdx.y * 128;
    const int c0 = tid, c1 = tid + 256;
    const int r0 = c0 >> 2, kq0 = (c0 & 3) * 8;
    const int r1 = c1 >> 2, kq1 = (c1 & 3) * 8;
    int ga0 = row0 + r0; if (ga0 >= M) ga0 = M - 1;
    int ga1 = row0 + r1; if (ga1 >= M) ga1 = M - 1;
    const short* Ab = A + (asel ? (col0 & 512) : 0);
    const short* Ap0 = Ab + (size_t)ga0 * lda + kq0;
    const short* Ap1 = Ab + (size_t)ga1 * lda + kq1;
    const short* Bp0 = Bt + (size_t)(col0 + r0) * K + kq0;
    const short* Bp1 = Bt + (size_t)(col0 + r1) * K + kq1;

    f32x4 acc[4][4];
#pragma unroll
    for (int i = 0; i < 4; ++i)
#pragma unroll
        for (int j = 0; j < 4; ++j)
            acc[i][j] = f32x4{0.f, 0.f, 0.f, 0.f};

    const int nsteps = K >> 5;
    // prologue: stage steps 0,1 into buffers 0,1
    gload16(Ap0, &As[c0 * 8]);
    gload16(Ap1, &As[c1 * 8]);
    gload16(Bp0, &Bs[c0 * 8]);
    gload16(Bp1, &Bs[c1 * 8]);
    gload16(Ap0 + 32, &As[4096 + c0 * 8]);
    gload16(Ap1 + 32, &As[4096 + c1 * 8]);
    gload16(Bp0 + 32, &Bs[4096 + c0 * 8]);
    gload16(Bp1 + 32, &Bs[4096 + c1 * 8]);
    int cur = 0, nx2 = 2;
#pragma unroll 1
    for (int ks = 0; ks < nsteps - 1; ++ks) {
        asm volatile("s_waitcnt vmcnt(4)" ::: "memory");
        __builtin_amdgcn_s_barrier();
        if (ks + 2 < nsteps) {
            const int kb = (ks + 2) * 32;
            const int nb = nx2 * 4096;
            gload16(Ap0 + kb, &As[nb + c0 * 8]);
            gload16(Ap1 + kb, &As[nb + c1 * 8]);
            gload16(Bp0 + kb, &Bs[nb + c0 * 8]);
            gload16(Bp1 + kb, &Bs[nb + c1 * 8]);
        }
        const int cb = cur * 4096;
        bf16x8 af[4], bfr[4];
#pragma unroll
        for (int i = 0; i < 4; ++i)
            af[i] = *(const bf16x8*)&As[cb + (wr + i * 16 + l16) * 32 + quad * 8];
#pragma unroll
        for (int j = 0; j < 4; ++j)
            bfr[j] = *(const bf16x8*)&Bs[cb + (wc + j * 16 + l16) * 32 + quad * 8];
#pragma unroll
        for (int i = 0; i < 4; ++i)
#pragma unroll
            for (int j = 0; j < 4; ++j)
                acc[i][j] = __builtin_amdgcn_mfma_f32_16x16x32_bf16(af[i], bfr[j], acc[i][j], 0, 0, 0);
        cur = (cur == 2) ? 0 : cur + 1;
        nx2 = (nx2 == 2) ? 0 : nx2 + 1;
    }
    {   // peeled last step: drain
        asm volatile("s_waitcnt vmcnt(0)" ::: "memory");
        __builtin_amdgcn_s_barrier();
        const int cb = cur * 4096;
        bf16x8 af[4], bfr[4];
#pragma unroll
        for (int i = 0; i < 4; ++i)
            af[i] = *(const bf16x8*)&As[cb + (wr + i * 16 + l16) * 32 + quad * 8];
#pragma unroll
        for (int j = 0; j < 4; ++j)
            bfr[j] = *(const bf16x8*)&Bs[cb + (wc + j * 16 + l16) * 32 + quad * 8];
#pragma unroll
        for (int i = 0; i < 4; ++i)
#pragma unroll
            for (int j = 0; j < 4; ++j)
                acc[i][j] = __builtin_amdgcn_mfma_f32_16x16x32_bf16(af[i], bfr[j], acc[i][j], 0, 0, 0);
    }
#pragma unroll
    for (int i = 0; i < 4; ++i) {
        int rbase = row0 + wr + i * 16 + quad * 4;
#pragma unroll
        for (int j = 0; j < 4; ++j) {
            int c = col0 + wc + j * 16 + l16;
            float bv = bias ? bias[c] : 0.0f;
#pragma unroll
            for (int rg = 0; rg < 4; ++rg) {
                int gr = rbase + rg;
                if (gr < M) {
                    float v = acc[i][j][rg] + bv;
                    if (act) v = gelu1(v);
                    C[(size_t)gr * ldc + c] = (short)f2bf1(v);
                    if (C8) {
                        int r8 = __builtin_amdgcn_cvt_pk_fp8_f32(v, v, 0, false);
                        C8[(size_t)gr * ldc + c] = (unsigned char)(r8 & 0xFF);
                    }
                    if (Cf) Cf[(size_t)gr * ldc + c] = v;
                }
            }
        }
    }
}

// ---------------- qkv GEMM, XCD-swizzled 1D grid, 3-buffer pipeline, split epilogue ---
// Same 2-deep counted-vmcnt pipeline as gemm_bb.
// Output cols: [0,512) q -> qvs (bf16) ; [512,1024) k -> kv8+0 (fp8) ;
// [1024,1536) v -> kv8+512 (fp8) ; [1536,2048) s -> qvs+512 (bf16).

__global__ __launch_bounds__(256) void gemm_qkvs(
    const short* __restrict__ A,      // h_bf [M][512]
    const short* __restrict__ Bt,     // layer weights [2048][512]
    const float* __restrict__ bias,   // [2048]
    short* __restrict__ qvs,          // [M][1024] bf16 (q|s)
    unsigned char* __restrict__ kv8,  // [M][1024] fp8 (k|v)
    int M, int mtiles) {
    const int K = 512;
    const int id = blockIdx.x;
    const int xcd = id & 7;
    const int t = id >> 3;
    const int col_t = t & 15;
    const int row_t = (t >> 4) * 8 + xcd;
    if (row_t >= mtiles) return;
    const int row0 = row_t * 128;
    const int col0 = col_t * 128;
    __shared__ __align__(16) short As[3 * 128 * 32];
    __shared__ __align__(16) short Bs[3 * 128 * 32];
    const int tid = threadIdx.x;
    const int lane = tid & 63;
    const int wave = tid >> 6;
    const int wr = (wave >> 1) * 64;
    const int wc = (wave & 1) * 64;
    const int l16 = lane & 15;
    const int quad = lane >> 4;
    const int c0 = tid, c1 = tid + 256;
    const int r0 = c0 >> 2, kq0 = (c0 & 3) * 8;
    const int r1 = c1 >> 2, kq1 = (c1 & 3) * 8;
    int ga0 = row0 + r0; if (ga0 >= M) ga0 = M - 1;
    int ga1 = row0 + r1; if (ga1 >= M) ga1 = M - 1;
    const short* Ap0 = A + (size_t)ga0 * K + kq0;
    const short* Ap1 = A + (size_t)ga1 * K + kq1;
    const short* Bp0 = Bt + (size_t)(col0 + r0) * K + kq0;
    const short* Bp1 = Bt + (size_t)(col0 + r1) * K + kq1;

    f32x4 acc[4][4];
#pragma unroll
    for (int i = 0; i < 4; ++i)
#pragma unroll
        for (int j = 0; j < 4; ++j)
            acc[i][j] = f32x4{0.f, 0.f, 0.f, 0.f};

    // prologue: stage steps 0,1 into buffers 0,1
    gload16(Ap0, &As[c0 * 8]);
    gload16(Ap1, &As[c1 * 8]);
    gload16(Bp0, &Bs[c0 * 8]);
    gload16(Bp1, &Bs[c1 * 8]);
    gload16(Ap0 + 32, &As[4096 + c0 * 8]);
    gload16(Ap1 + 32, &As[4096 + c1 * 8]);
    gload16(Bp0 + 32, &Bs[4096 + c0 * 8]);
    gload16(Bp1 + 32, &Bs[4096 + c1 * 8]);
    int cur = 0, nx2 = 2;
#pragma unroll 1
    for (int ks = 0; ks < 15; ++ks) {
        asm volatile("s_waitcnt vmcnt(4)" ::: "memory");
        __builtin_amdgcn_s_barrier();
        if (ks + 2 < 16) {
            const int kb = (ks + 2) * 32;
            const int nb = nx2 * 4096;
            gload16(Ap0 + kb, &As[nb + c0 * 8]);
            gload16(Ap1 + kb, &As[nb + c1 * 8]);
            gload16(Bp0 + kb, &Bs[nb + c0 * 8]);
            gload16(Bp1 + kb, &Bs[nb + c1 * 8]);
        }
        const int cb = cur * 4096;
        bf16x8 af[4], bfr[4];
#pragma unroll
        for (int i = 0; i < 4; ++i)
            af[i] = *(const bf16x8*)&As[cb + (wr + i * 16 + l16) * 32 + quad * 8];
#pragma unroll
        for (int j = 0; j < 4; ++j)
            bfr[j] = *(const bf16x8*)&Bs[cb + (wc + j * 16 + l16) * 32 + quad * 8];
#pragma unroll
        for (int i = 0; i < 4; ++i)
#pragma unroll
            for (int j = 0; j < 4; ++j)
                acc[i][j] = __builtin_amdgcn_mfma_f32_16x16x32_bf16(af[i], bfr[j], acc[i][j], 0, 0, 0);
        cur = (cur == 2) ? 0 : cur + 1;
        nx2 = (nx2 == 2) ? 0 : nx2 + 1;
    }
    {   // peeled last step
        asm volatile("s_waitcnt vmcnt(0)" ::: "memory");
        __builtin_amdgcn_s_barrier();
        const int cb = cur * 4096;
        bf16x8 af[4], bfr[4];
#pragma unroll
        for (int i = 0; i < 4; ++i)
            af[i] = *(const bf16x8*)&As[cb + (wr + i * 16 + l16) * 32 + quad * 8];
#pragma unroll
        for (int j = 0; j < 4; ++j)
            bfr[j] = *(const bf16x8*)&Bs[cb + (wc + j * 16 + l16) * 32 + quad * 8];
#pragma unroll
        for (int i = 0; i < 4; ++i)
#pragma unroll
            for (int j = 0; j < 4; ++j)
                acc[i][j] = __builtin_amdgcn_mfma_f32_16x16x32_bf16(af[i], bfr[j], acc[i][j], 0, 0, 0);
    }
#pragma unroll
    for (int i = 0; i < 4; ++i) {
        int rbase = row0 + wr + i * 16 + quad * 4;
#pragma unroll
        for (int j = 0; j < 4; ++j) {
            int c = col0 + wc + j * 16 + l16;
            int sec = c >> 9;           // uniform within a 64-col wave tile
            int cc = c & 511;
            float bv = bias[c];
#pragma unroll
            for (int rg = 0; rg < 4; ++rg) {
                int gr = rbase + rg;
                if (gr < M) {
                    float v = acc[i][j][rg] + bv;
                    if (sec == 1 || sec == 2) {
                        int r8 = __builtin_amdgcn_cvt_pk_fp8_f32(v, v, 0, false);
                        int off = (sec == 1) ? cc : 512 + cc;
                        kv8[(size_t)gr * 1024 + off] = (unsigned char)(r8 & 0xFF);
                    } else {
                        int off = (sec == 0) ? cc : 512 + cc;
                        qvs[(size_t)gr * 1024 + off] = (short)f2bf1(v);
                    }
                }
            }
        }
    }
}

// ---------------- fused gate GEMM v3 + final combine ---------------------------------
// 128 pairs x 512 cols per block, 512 thr (2Mx4N waves), acc[4][8] (AGPRs).
// Counted s_waitcnt keeps staged loads in flight across raw s_barriers (T3/T4).
// NO setprio (m190/R6: -31% on this lockstep structure). Register-locked at
// 2 waves/SIMD. R11: k_final folded into the epilogue (reads ssyn/sant/gb2,
// writes out directly) — removes one launch + the gpart global round-trip.

__global__ __launch_bounds__(512, 2) void gemm_gate(
    const unsigned char* __restrict__ z8,   // [Nn][1024] fp8
    const int* __restrict__ pi, const int* __restrict__ pj, int P,
    const short* __restrict__ Bt,    // gW1^T [512][2048], pre-swizzled
    const float* __restrict__ gb1,
    const float* __restrict__ gW2,
    const float* __restrict__ gb2,
    const float* __restrict__ ssyn,
    const float* __restrict__ sant,
    float* __restrict__ out) {
    __shared__ __align__(16) short Bab[2 * 512 * 32];   // 64 KB
    __shared__ __align__(16) short Bmu[2 * 512 * 32];   // 64 KB
    __shared__ __align__(16) short Asab[128 * 32];      // 8 KB
    __shared__ __align__(16) short Asmu[128 * 32];      // 8 KB
    __shared__ int iArr[128];
    __shared__ int jArr[128];
    __shared__ float rowsum[128];
    const int row0 = blockIdx.x * 128;
    const int tid = threadIdx.x;
    const int lane = tid & 63;
    const int wave = tid >> 6;       // 0..7
    const int wm = wave >> 2;        // 0..1 : 64-row group
    const int wn = wave & 3;         // 0..3 : 128-col group
    const int l16 = lane & 15;
    const int quad = lane >> 4;
    const int arow = tid >> 2;       // 0..127
    const int aslot = tid & 3;
    const int qs = (quad ^ ((l16 >> 1) & 3)) * 8;                       // read swizzle
    const int awoff = arow * 32 + ((aslot ^ ((arow >> 1) & 3)) << 3);   // write swizzle

    if (tid < 128) {
        int p = row0 + tid;
        int ok = (p < P);
        iArr[tid] = ok ? pi[p] : 0;
        jArr[tid] = ok ? pj[p] : 0;
        rowsum[tid] = 0.0f;
    }
    __syncthreads();
    const unsigned char* zi = z8 + (size_t)iArr[arow] * 1024 + aslot * 8;
    const unsigned char* zj = z8 + (size_t)jArr[arow] * 1024 + aslot * 8;
    const short* brow = Bt + (size_t)(tid >> 2) * 2048 + (tid & 3) * 8;

    f32x4 acc[4][8];
#pragma unroll
    for (int i = 0; i < 4; ++i)
#pragma unroll
        for (int j = 0; j < 8; ++j)
            acc[i][j] = f32x4{0.f, 0.f, 0.f, 0.f};

    // B source offset (shorts) for k-chunk kc: part = kc>>4, chan = (kc&15)*32
    auto CHB = [](int kc) { return ((kc >> 4) << 10) + ((kc & 15) << 5); };
    // z byte offset for k-chunk kc
    auto KOFF = [](int kc) { return ((kc >> 4) << 9) + ((kc & 15) << 5); };
    auto STAGE = [&](int kc, int mu, short* buf) {
        const short* src = brow + CHB(kc) + (mu ? 512 : 0);
#pragma unroll
        for (int g = 0; g < 4; ++g)
            gload16(src + (size_t)(g * 128) * 2048, buf + (g * 512 + tid) * 8);
    };
    auto CVT = [&](uint2 xu, uint2 yu, uint4& aa, uint4& am) {
        f32x2 x0 = __builtin_amdgcn_cvt_pk_f32_fp8((int)xu.x, false);
        f32x2 x1 = __builtin_amdgcn_cvt_pk_f32_fp8((int)xu.x, true);
        f32x2 x2 = __builtin_amdgcn_cvt_pk_f32_fp8((int)xu.y, false);
        f32x2 x3 = __builtin_amdgcn_cvt_pk_f32_fp8((int)xu.y, true);
        f32x2 y0 = __builtin_amdgcn_cvt_pk_f32_fp8((int)yu.x, false);
        f32x2 y1 = __builtin_amdgcn_cvt_pk_f32_fp8((int)yu.x, true);
        f32x2 y2 = __builtin_amdgcn_cvt_pk_f32_fp8((int)yu.y, false);
        f32x2 y3 = __builtin_amdgcn_cvt_pk_f32_fp8((int)yu.y, true);
        aa.x = cvt_pk_bf16(fabsf(x0.x - y0.x), fabsf(x0.y - y0.y));
        aa.y = cvt_pk_bf16(fabsf(x1.x - y1.x), fabsf(x1.y - y1.y));
        aa.z = cvt_pk_bf16(fabsf(x2.x - y2.x), fabsf(x2.y - y2.y));
        aa.w = cvt_pk_bf16(fabsf(x3.x - y3.x), fabsf(x3.y - y3.y));
        am.x = cvt_pk_bf16(x0.x * y0.x, x0.y * y0.y);
        am.y = cvt_pk_bf16(x1.x * y1.x, x1.y * y1.y);
        am.z = cvt_pk_bf16(x2.x * y2.x, x2.y * y2.y);
        am.w = cvt_pk_bf16(x3.x * y3.x, x3.y * y3.y);
    };
    auto MFMA_PHASE = [&](const short* As, const short* Bp) {
        bf16x8 af[4];
#pragma unroll
        for (int i = 0; i < 4; ++i)
            af[i] = *(const bf16x8*)&As[(wm * 64 + i * 16 + l16) * 32 + qs];
#pragma unroll
        for (int j = 0; j < 8; ++j) {
            bf16x8 bf = *(const bf16x8*)&Bp[(wn * 128 + j * 16 + l16) * 32 + qs];
#pragma unroll
            for (int i = 0; i < 4; ++i)
                acc[i][j] = __builtin_amdgcn_mfma_f32_16x16x32_bf16(af[i], bf, acc[i][j], 0, 0, 0);
        }
    };

    // ---- prologue: stage AB(0), load z(0), cvt (implicit z-wait retires AB(0)) ----
    STAGE(0, 0, Bab);
    uint2 xu = *(const uint2*)zi;
    uint2 yu = *(const uint2*)zj;
    uint4 aa, am, am_hold;
    CVT(xu, yu, aa, am);
    *(uint4*)&Asab[awoff] = aa;
    am_hold = am;

#pragma unroll 1
    for (int kc = 0; kc < 31; ++kc) {
        const int cur = kc & 1;
        // ---- AB sub-phase ----
        STAGE(kc, 1, Bmu + cur * 16384);
        uint2 xn = *(const uint2*)(zi + KOFF(kc + 1));
        uint2 yn = *(const uint2*)(zj + KOFF(kc + 1));
        asm volatile("s_waitcnt vmcnt(6) lgkmcnt(0)" ::: "memory");
        __builtin_amdgcn_s_barrier();
        MFMA_PHASE(Asab, Bab + cur * 16384);
        *(uint4*)&Asmu[awoff] = am_hold;          // post-section write (for mu of this kc)
        // ---- MU sub-phase ----
        STAGE(kc + 1, 0, Bab + (cur ^ 1) * 16384);
        CVT(xn, yn, aa, am);                      // implicit z-wait retires Bmu[cur]
        asm volatile("s_waitcnt vmcnt(4) lgkmcnt(0)" ::: "memory");
        __builtin_amdgcn_s_barrier();
        MFMA_PHASE(Asmu, Bmu + cur * 16384);
        *(uint4*)&Asab[awoff] = aa;               // post-section write (for ab of kc+1)
        am_hold = am;
    }
    // ---- tail kc = 31 (cur = 1) ----
    STAGE(31, 1, Bmu + 16384);
    asm volatile("s_waitcnt vmcnt(4) lgkmcnt(0)" ::: "memory");
    __builtin_amdgcn_s_barrier();
    MFMA_PHASE(Asab, Bab + 16384);
    *(uint4*)&Asmu[awoff] = am_hold;
    asm volatile("s_waitcnt vmcnt(0) lgkmcnt(0)" ::: "memory");
    __builtin_amdgcn_s_barrier();
    MFMA_PHASE(Asmu, Bmu + 16384);

    // ---- epilogue: fused gelu + gW2 dot, per-row reduce, sigmoid combine ----
#pragma unroll
    for (int i = 0; i < 4; ++i) {
#pragma unroll
        for (int rg = 0; rg < 4; ++rg) {
            float partial = 0.f;
#pragma unroll
            for (int j = 0; j < 8; ++j) {
                int cc = wn * 128 + j * 16 + l16;
                partial += gelu1(acc[i][j][rg] + gb1[cc]) * gW2[cc];
            }
            partial += __shfl_xor(partial, 1);
            partial += __shfl_xor(partial, 2);
            partial += __shfl_xor(partial, 4);
            partial += __shfl_xor(partial, 8);
            if (l16 == 0)
                atomicAdd(&rowsum[wm * 64 + i * 16 + quad * 4 + rg], partial);
        }
    }
    __syncthreads();
    if (tid < 128) {
        int p = row0 + tid;
        if (p < P) {
            float s = 1.0f / (1.0f + __expf(-(rowsum[tid] + gb2[0])));
            out[p] = s * sant[p] - (1.0f - s) * ssyn[p];
        }
    }
}

// ---------------- fused per-layer attention: single-pass, fp8 k AND v gather ----------
// qvs bf16 [Nn][1024] (q|s), kv8 fp8 [Nn][1024] (k|v). Per edge: 8B k + 8B v per lane.
// R11: edge loop unrolled 8-deep (R7's 4-deep gave -40us; avg degree 16 so 8-deep
// covers a chunk in 2 iters, doubling scattered loads in flight). Sequential
// online-softmax order preserved (numerics identical).

__global__ __launch_bounds__(256) void k_attn(const short* __restrict__ qvs,
                                              const unsigned char* __restrict__ kv8,
                                              const int* __restrict__ srcS,
                                              const int* __restrict__ offs,
                                              float* __restrict__ h,
                                              short* __restrict__ h_bf,
                                              const float* __restrict__ lng,
                                              const float* __restrict__ lnb, int Nn) {
    const int tid = threadIdx.x;
    const int lane = tid & 63;
    const int wv = tid >> 6;
    const int n = blockIdx.x * 4 + wv;
    if (n >= Nn) return;
    const int st = offs[n], en = offs[n + 1];
    const size_t chOff = (size_t)lane * 8;

    uint4 qv = *(const uint4*)(qvs + (size_t)n * 1024 + chOff);
    float2 q0 = bfp2(qv.x), q1 = bfp2(qv.y), q2 = bfp2(qv.z), q3 = bfp2(qv.w);
    float acc[8];
#pragma unroll
    for (int i = 0; i < 8; ++i) acc[i] = 0.f;
    float m_l = -3.4e38f, l_l = 0.f;

    auto PROC = [&](uint2 kq, uint2 vq) {
        f32x2 k0 = __builtin_amdgcn_cvt_pk_f32_fp8((int)kq.x, false);
        f32x2 k1 = __builtin_amdgcn_cvt_pk_f32_fp8((int)kq.x, true);
        f32x2 k2 = __builtin_amdgcn_cvt_pk_f32_fp8((int)kq.y, false);
        f32x2 k3 = __builtin_amdgcn_cvt_pk_f32_fp8((int)kq.y, true);
        float d = q0.x * k0.x + q0.y * k0.y + q1.x * k1.x + q1.y * k1.y +
                  q2.x * k2.x + q2.y * k2.y + q3.x * k3.x + q3.y * k3.y;
        d += __shfl_xor(d, 1);
        d += __shfl_xor(d, 2);
        d += __shfl_xor(d, 4);
        d += __shfl_xor(d, 8);
        float lg = d * 0.08838834764831845f;
        float m_new = fmaxf(m_l, lg);
        float sc = __expf(m_l - m_new);
        float p = __expf(lg - m_new);
        l_l = l_l * sc + p;
        m_l = m_new;
        f32x2 v0 = __builtin_amdgcn_cvt_pk_f32_fp8((int)vq.x, false);
        f32x2 v1 = __builtin_amdgcn_cvt_pk_f32_fp8((int)vq.x, true);
        f32x2 v2 = __builtin_amdgcn_cvt_pk_f32_fp8((int)vq.y, false);
        f32x2 v3 = __builtin_amdgcn_cvt_pk_f32_fp8((int)vq.y, true);
        acc[0] = acc[0] * sc + p * v0.x; acc[1] = acc[1] * sc + p * v0.y;
        acc[2] = acc[2] * sc + p * v1.x; acc[3] = acc[3] * sc + p * v1.y;
        acc[4] = acc[4] * sc + p * v2.x; acc[5] = acc[5] * sc + p * v2.y;
        acc[6] = acc[6] * sc + p * v3.x; acc[7] = acc[7] * sc + p * v3.y;
    };

    for (int e0 = st; e0 < en; e0 += 64) {
        int cnt = min(64, en - e0);
        int myS = (lane < cnt) ? srcS[e0 + lane] : 0;
        int ei = 0;
        for (; ei + 8 <= cnt; ei += 8) {
            const unsigned char* rp[8];
#pragma unroll
            for (int u = 0; u < 8; ++u) {
                int s = __shfl(myS, ei + u);
                rp[u] = kv8 + (size_t)s * 1024 + chOff;
            }
            uint2 kk[8], vv[8];
#pragma unroll
            for (int u = 0; u < 8; ++u) {
                kk[u] = *(const uint2*)rp[u];
                vv[u] = *(const uint2*)(rp[u] + 512);
            }
#pragma unroll
            for (int u = 0; u < 8; ++u) PROC(kk[u], vv[u]);
        }
        for (; ei < cnt; ++ei) {
            int s = __shfl(myS, ei);
            const unsigned char* srow = kv8 + (size_t)s * 1024 + chOff;
            uint2 kq = *(const uint2*)srow;
            uint2 vq = *(const uint2*)(srow + 512);
            PROC(kq, vq);
        }
    }
    float rinv = (en > st) ? 1.0f / l_l : 0.f;
    uint4 su = *(const uint4*)(qvs + (size_t)n * 1024 + 512 + chOff);
    float2 s0 = bfp2(su.x), s1 = bfp2(su.y), s2 = bfp2(su.z), s3 = bfp2(su.w);
    float sv[8] = {s0.x, s0.y, s1.x, s1.y, s2.x, s2.y, s3.x, s3.y};
    const float* hp = h + (size_t)n * 512 + chOff;
    float4 h0 = *(const float4*)hp;
    float4 h1 = *(const float4*)(hp + 4);
    float hv[8] = {h0.x, h0.y, h0.z, h0.w, h1.x, h1.y, h1.z, h1.w};
    float r[8];
    float sum = 0.f, ssq = 0.f;
#pragma unroll
    for (int i = 0; i < 8; ++i) {
        r[i] = hv[i] + gelu1(acc[i] * rinv + sv[i]);
        sum += r[i];
        ssq += r[i] * r[i];
    }
    for (int o = 32; o; o >>= 1) {
        sum += __shfl_xor(sum, o);
        ssq += __shfl_xor(ssq, o);
    }
    float mean = sum * (1.0f / 512.0f);
    float var = ssq * (1.0f / 512.0f) - mean * mean;
    float inv = rsqrtf(var + 1e-5f);
    const float* gp = lng + chOff;
    const float* bp = lnb + chOff;
    float4 g0 = *(const float4*)gp, g1 = *(const float4*)(gp + 4);
    float4 b0 = *(const float4*)bp, b1 = *(const float4*)(bp + 4);
    float ga[8] = {g0.x, g0.y, g0.z, g0.w, g1.x, g1.y, g1.z, g1.w};
    float ba[8] = {b0.x, b0.y, b0.z, b0.w, b1.x, b1.y, b1.z, b1.w};
    float o8[8];
#pragma unroll
    for (int i = 0; i < 8; ++i) o8[i] = (r[i] - mean) * inv * ga[i] + ba[i];
    float* hw = h + (size_t)n * 512 + chOff;
    *(float4*)hw = make_float4(o8[0], o8[1], o8[2], o8[3]);
    *(float4*)(hw + 4) = make_float4(o8[4], o8[5], o8[6], o8[7]);
    uint4 ob;
    ob.x = f2bf2(o8[0], o8[1]);
    ob.y = f2bf2(o8[2], o8[3]);
    ob.z = f2bf2(o8[4], o8[5]);
    ob.w = f2bf2(o8[6], o8[7]);
    *(uint4*)(h_bf + (size_t)n * 512 + chOff) = ob;
}

// ---------------- pair bilinear scores (bf16 z,t) ----------------

__global__ __launch_bounds__(256) void k_pairscore(const short* __restrict__ z,
                                                   const short* __restrict__ t,
                                                   const int* __restrict__ pi,
                                                   const int* __restrict__ pj,
                                                   float* __restrict__ ssyn,
                                                   float* __restrict__ sant, int P) {
    int p = blockIdx.x * 4 + (threadIdx.x >> 6);
    if (p >= P) return;
    int lane = threadIdx.x & 63;
    int i = pi[p], j = pj[p];
    uint4 a = *(const uint4*)(t + (size_t)i * 1024 + lane * 8);
    uint4 b = *(const uint4*)(z + (size_t)j * 1024 + lane * 8);
    float2 a0 = bfp2(a.x), a1 = bfp2(a.y), a2 = bfp2(a.z), a3 = bfp2(a.w);
    float2 b0 = bfp2(b.x), b1 = bfp2(b.y), b2 = bfp2(b.z), b3 = bfp2(b.w);
    float ds = a0.x * b0.x + a0.y * b0.y + a1.x * b1.x + a1.y * b1.y +
               a2.x * b2.x + a2.y * b2.y + a3.x * b3.x + a3.y * b3.y;
    uint4 c = *(const uint4*)(t + (size_t)i * 1024 + 512 + lane * 8);
    uint4 d = *(const uint4*)(z + (size_t)j * 1024 + 512 + lane * 8);
    float2 c0 = bfp2(c.x), c1 = bfp2(c.y), c2 = bfp2(c.z), c3 = bfp2(c.w);
    float2 d0 = bfp2(d.x), d1 = bfp2(d.y), d2 = bfp2(d.z), d3 = bfp2(d.w);
    float da = c0.x * d0.x + c0.y * d0.y + c1.x * d1.x + c1.y * d1.y +
               c2.x * d2.x + c2.y * d2.y + c3.x * d3.x + c3.y * d3.y;
    for (int o = 32; o; o >>= 1) {
        ds += __shfl_xor(ds, o);
        da += __shfl_xor(da, o);
    }
    if (lane == 0) { ssyn[p] = ds; sant[p] = da; }
}

// ---------------- host ----------------

extern "C" void kernel_launch(void* const* d_in, const int* in_sizes, int n_in,
                              void* d_out, int out_size, void* d_ws, size_t ws_size,
                              hipStream_t stream) {
    const float* x = (const float*)d_in[0];
    const int* ei = (const int*)d_in[1];
    const int* pe = (const int*)d_in[2];
    const float* mixer_W = (const float*)d_in[3];
    const float* mixer_b = (const float*)d_in[4];
    const float* Wq = (const float*)d_in[5];
    const float* bq = (const float*)d_in[6];
    const float* Wk = (const float*)d_in[7];
    const float* bk = (const float*)d_in[8];
    const float* Wv = (const float*)d_in[9];
    const float* bv = (const float*)d_in[10];
    const float* Ws = (const float*)d_in[11];
    const float* bs = (const float*)d_in[12];
    const float* ln_g = (const float*)d_in[13];
    const float* ln_b = (const float*)d_in[14];
    const float* syn_W = (const float*)d_in[15];
    const float* syn_b = (const float*)d_in[16];
    const float* ant_W = (const float*)d_in[17];
    const float* ant_b = (const float*)d_in[18];
    const float* W_syn = (const float*)d_in[19];
    const float* W_ant = (const float*)d_in[20];
    const float* gW1 = (const float*)d_in[21];
    const float* gb1 = (const float*)d_in[22];
    const float* gW2 = (const float*)d_in[23];
    const float* gb2 = (const float*)d_in[24];
    float* out = (float*)d_out;

    const int Nn = in_sizes[0] / 768;  // 20000
    const int E = in_sizes[1] / 2;     // 320000
    const int P = in_sizes[2] / 2;     // 100000

    char* w = (char*)d_ws;
    auto alloc = [&](size_t bytes) -> char* {
        char* p = w;
        w += (bytes + 255) & ~(size_t)255;
        return p;
    };
    float* h = (float*)alloc((size_t)Nn * 512 * 4);
    short* h_bf = (short*)alloc((size_t)Nn * 512 * 2);
    // union region U: pre-mixer = x_bf [Nn][768] bf16 ; during layers = qvs [Nn][1024]
    // bf16 (q|s) + kv8 [Nn][1024] fp8 (k|v) ; after layers = zB | tB (bf16)
    char* U = alloc((size_t)Nn * 2048 * 2);
    short* x_bf = (short*)U;                      // 30.7 MB < |U|; dead after mixer
    short* qvs = (short*)U;
    unsigned char* kv8 = (unsigned char*)(U + (size_t)Nn * 1024 * 2);
    short* zB = (short*)U;
    short* tB = (short*)(U + (size_t)Nn * 1024 * 2);
    unsigned char* z8 = (unsigned char*)alloc((size_t)Nn * 1024);   // fp8 z copy, 20 MB
    float* ssyn = (float*)alloc((size_t)P * 2 * 4);
    float* sant = ssyn + P;
    int* srcS = (int*)alloc((size_t)E * 4);
    int* hist = (int*)alloc((size_t)Nn * 2 * 4);
    int* cursor = hist + Nn;
    int* offs = (int*)alloc((size_t)(Nn + 1) * 4);
    short* mixWt = (short*)alloc((size_t)512 * 768 * 2);
    short* wcat = (short*)alloc((size_t)L_LAYERS * 2048 * 512 * 2);
    short* dualWt = (short*)alloc((size_t)1024 * 512 * 2);
    short* bilWt = (short*)alloc((size_t)1024 * 512 * 2);
    short* gw1t = (short*)alloc((size_t)512 * 2048 * 2);
    float* bcat = (float*)alloc((size_t)L_LAYERS * 2048 * 4);
    float* bdual = (float*)alloc((size_t)1024 * 4);

    k_zero<<<(2 * Nn + 255) / 256, 256, 0, stream>>>(hist, 2 * Nn);
    k_hist<<<(E + 255) / 256, 256, 0, stream>>>(ei + E, hist, E);
    k_scan<<<1, 1024, 0, stream>>>(hist, offs, Nn);
    k_scatter<<<(E + 255) / 256, 256, 0, stream>>>(ei, ei + E, offs, cursor, srcS, E);

    k_wcat<<<(L_LAYERS * 2048 * 512) / 256, 256, 0, stream>>>(Wq, Wk, Wv, Ws, wcat);
    k_tr<<<dim3(3, 512), 256, 0, stream>>>(mixer_W, mixWt, 768, 512, 0);
    k_tr<<<dim3(2, 512), 256, 0, stream>>>(syn_W, dualWt, 512, 512, 0);
    k_tr<<<dim3(2, 512), 256, 0, stream>>>(ant_W, dualWt + 512 * 512, 512, 512, 0);
    k_tr<<<dim3(2, 512), 256, 0, stream>>>(W_syn, bilWt, 512, 512, 0);
    k_tr<<<dim3(2, 512), 256, 0, stream>>>(W_ant, bilWt + 512 * 512, 512, 512, 0);
    k_tr<<<dim3(8, 512), 256, 0, stream>>>(gW1, gw1t, 2048, 512, 1);   // pre-swizzled for gemm_gate
    k_bcat<<<48, 256, 0, stream>>>(bq, bk, bv, bs, bcat);
    k_bdual<<<4, 256, 0, stream>>>(syn_b, ant_b, bdual);

    const int mtiles = (Nn + 127) / 128;  // 157
    // mixer: x -> bf16 once, then gload_lds GEMM (replaces VALU-bound gemm_a32)
    k_cvt<<<(Nn * 768 / 8 + 255) / 256, 256, 0, stream>>>(x, x_bf, Nn * 768 / 8);
    gemm_bb<<<dim3(mtiles, 4), 256, 0, stream>>>(x_bf, 768, mixWt, mixer_b, h_bf,
                                                 nullptr, h, 512, Nn, 512, 768, 1, 0);

    // XCD-swizzled 1D grid: ceil(mtiles/8)*8 row slots x 16 col tiles
    const int qk_grid = ((mtiles + 7) / 8) * 8 * 16;   // 2560
    for (int l = 0; l < L_LAYERS; ++l) {
        gemm_qkvs<<<qk_grid, 256, 0, stream>>>(h_bf, wcat + (size_t)l * 2048 * 512,
                                               bcat + l * 2048, qvs, kv8, Nn, mtiles);
        k_attn<<<(Nn + 3) / 4, 256, 0, stream>>>(qvs, kv8, srcS, offs, h, h_bf,
                                                 ln_g + l * 512, ln_b + l * 512, Nn);
    }

    // z = gelu(h @ [syn_W|ant_W] + b) -> zB bf16 + z8 fp8
    gemm_bb<<<dim3(mtiles, 8), 256, 0, stream>>>(h_bf, 512, dualWt, bdual, zB, z8,
                                                 nullptr, 1024, Nn, 1024, 512, 1, 0);
    // merged bilinear: tB[:,0:512] = zB[:,0:512]@W_syn^T ; tB[:,512:] = zB[:,512:]@W_ant^T
    gemm_bb<<<dim3(mtiles, 8), 256, 0, stream>>>(zB, 1024, bilWt, nullptr, tB, nullptr,
                                                 nullptr, 1024, Nn, 1024, 512, 0, 1);

    k_pairscore<<<(P + 3) / 4, 256, 0, stream>>>(zB, tB, pe, pe + P, ssyn, sant, P);

    const int ptiles2 = (P + 127) / 128;               // 782
    gemm_gate<<<ptiles2, 512, 0, stream>>>(z8, pe, pe + P, P, gw1t, gb1, gW2,
                                           gb2, ssyn, sant, out);
}

// Round 12
// 1598.373 us; speedup vs baseline: 1.0109x; 1.0109x over previous
//
#include <hip/hip_runtime.h>
#include <cstdint>

#define L_LAYERS 6

typedef __attribute__((ext_vector_type(8))) short bf16x8;
typedef __attribute__((ext_vector_type(4))) float f32x4;
typedef __attribute__((ext_vector_type(2))) float f32x2;

__device__ __forceinline__ float gelu1(float v) {
    return 0.5f * v * (1.0f + erff(v * 0.7071067811865475f));
}

__device__ __forceinline__ unsigned int f2bf2(float a, float b) {
    union { float f; unsigned u; } x, y;
    x.f = a; y.f = b;
    unsigned lo = (x.u + 0x7FFFu + ((x.u >> 16) & 1u)) >> 16;
    unsigned hi = (y.u + 0x7FFFu + ((y.u >> 16) & 1u)) & 0xFFFF0000u;
    return lo | hi;
}

__device__ __forceinline__ unsigned short f2bf1(float a) {
    union { float f; unsigned u; } x;
    x.f = a;
    return (unsigned short)((x.u + 0x7FFFu + ((x.u >> 16) & 1u)) >> 16);
}

// single-instruction RNE pack of two f32 -> packed bf16x2 (same rounding as f2bf2)
__device__ __forceinline__ unsigned cvt_pk_bf16(float lo, float hi) {
    unsigned r;
    asm("v_cvt_pk_bf16_f32 %0, %1, %2" : "=v"(r) : "v"(lo), "v"(hi));
    return r;
}

__device__ __forceinline__ float2 bfp2(unsigned u) {
    union { unsigned u; float f; } a, b;
    a.u = u << 16;
    b.u = u & 0xFFFF0000u;
    return make_float2(a.f, b.f);
}

// async global->LDS, 16 bytes per lane (dest = wave-uniform base + lane*16)
__device__ __forceinline__ void gload16(const void* g, void* l) {
    __builtin_amdgcn_global_load_lds(
        (const __attribute__((address_space(1))) void*)g,
        (__attribute__((address_space(3))) void*)l, 16, 0, 0);
}

// ---------------- utility ----------------

__global__ void k_zero(int* __restrict__ p, int n) {
    int i = blockIdx.x * 256 + threadIdx.x;
    if (i < n) p[i] = 0;
}

// f32 -> bf16 bulk convert (8 elems/thread, fully vectorized; G13)
__global__ void k_cvt(const float* __restrict__ x, short* __restrict__ xb, int n8) {
    int i = blockIdx.x * 256 + threadIdx.x;
    if (i < n8) {
        const float4* p = (const float4*)(x + (size_t)i * 8);
        float4 a0 = p[0], a1 = p[1];
        uint4 o;
        o.x = f2bf2(a0.x, a0.y);
        o.y = f2bf2(a0.z, a0.w);
        o.z = f2bf2(a1.x, a1.y);
        o.w = f2bf2(a1.z, a1.w);
        *(uint4*)(xb + (size_t)i * 8) = o;
    }
}

// ---------------- edge sorting (counting sort by dst) ----------------

__global__ void k_hist(const int* __restrict__ dst, int* __restrict__ hist, int E) {
    int e = blockIdx.x * 256 + threadIdx.x;
    if (e < E) atomicAdd(&hist[dst[e]], 1);
}

__global__ __launch_bounds__(1024) void k_scan(const int* __restrict__ hist,
                                               int* __restrict__ off, int n) {
    __shared__ int buf[1024];
    __shared__ int carry;
    int tid = threadIdx.x;
    if (tid == 0) carry = 0;
    __syncthreads();
    for (int base = 0; base < n; base += 1024) {
        int v = (base + tid < n) ? hist[base + tid] : 0;
        buf[tid] = v;
        __syncthreads();
        int x = v;
        for (int o = 1; o < 1024; o <<= 1) {
            int t = (tid >= o) ? buf[tid - o] : 0;
            __syncthreads();
            x += t;
            buf[tid] = x;
            __syncthreads();
        }
        int c = carry;
        if (base + tid < n) off[base + tid] = c + x - v;   // exclusive
        __syncthreads();
        if (tid == 1023) carry = c + buf[1023];
        __syncthreads();
    }
    if (tid == 0) off[n] = carry;
}

__global__ void k_scatter(const int* __restrict__ src, const int* __restrict__ dst,
                          const int* __restrict__ off, int* __restrict__ cursor,
                          int* __restrict__ srcS, int E) {
    int e = blockIdx.x * 256 + threadIdx.x;
    if (e < E) {
        int d = dst[e];
        int pos = off[d] + atomicAdd(&cursor[d], 1);
        srcS[pos] = src[e];
    }
}

// ---------------- weight prep (transpose + cvt to bf16) ----------------

__global__ void k_wcat(const float* __restrict__ Wq, const float* __restrict__ Wk,
                       const float* __restrict__ Wv, const float* __restrict__ Ws,
                       short* __restrict__ Wt) {
    int idx = blockIdx.x * 256 + threadIdx.x;   // l*2^20 + n*512 + k
    int k = idx & 511;
    int nf = (idx >> 9) & 2047;
    int l = idx >> 20;
    int sel = nf >> 9, nn = nf & 511;
    const float* W = (sel == 0) ? Wq : (sel == 1) ? Wk : (sel == 2) ? Wv : Ws;
    float v = W[((size_t)l * 512 + k) * 512 + nn];
    Wt[idx] = (short)f2bf1(v);
}

// swz=1: XOR-permute 16B sub-blocks within each 64B k-chunk by ((n>>1)&3) so that
// linear global_load_lds staging + swizzled ds_read in gemm_gate is conflict-free.
__global__ void k_tr(const float* __restrict__ W, short* __restrict__ Wt, int K, int N,
                     int swz) {
    int k = blockIdx.x * 256 + threadIdx.x;
    int n = blockIdx.y;
    if (k < K) {
        int kk = k;
        if (swz) kk = (k & ~31) | (((((k >> 3) & 3) ^ ((n >> 1) & 3))) << 3) | (k & 7);
        Wt[(size_t)n * K + kk] = (short)f2bf1(W[(size_t)k * N + n]);
    }
}

__global__ void k_bcat(const float* __restrict__ bq, const float* __restrict__ bk,
                       const float* __restrict__ bv, const float* __restrict__ bs,
                       float* __restrict__ bcat) {
    int idx = blockIdx.x * 256 + threadIdx.x;
    if (idx >= L_LAYERS * 2048) return;
    int l = idx >> 11, n = idx & 2047;
    int sel = n >> 9, nn = n & 511;
    const float* b = (sel == 0) ? bq : (sel == 1) ? bk : (sel == 2) ? bv : bs;
    bcat[idx] = b[l * 512 + nn];
}

__global__ void k_bdual(const float* __restrict__ sb, const float* __restrict__ ab,
                        float* __restrict__ bd) {
    int idx = blockIdx.x * 256 + threadIdx.x;
    if (idx < 1024) bd[idx] = (idx < 512) ? sb[idx] : ab[idx - 512];
}

// ---------------- GEMM: A bf16, B bf16, 3-buffer 2-deep pipelined staging -------------
// Stage k+2 issued right after barrier k (2 compute iterations of cover), counted
// vmcnt(4) at top retires exactly stage k. NO setprio (m190/R6). Tail peeled.
// Requires K >= 96 (>=3 steps); call sites use K=512/768.
// Optional outputs: C8 (fp8 e4m3 copy), Cf (f32 copy, for the mixer's residual h).
// asel=1: block-diagonal mode for the merged bilinear GEMM — A column base is
// (col0 & 512), so C[:,0:512] = A[:,0:512]@Bt[0:512] and C[:,512:] = A[:,512:]@Bt[512:].

__global__ __launch_bounds__(256) void gemm_bb(
    const short* __restrict__ A, int lda,
    const short* __restrict__ Bt,
    const float* __restrict__ bias,
    short* __restrict__ C, unsigned char* __restrict__ C8, float* __restrict__ Cf,
    int ldc, int M, int N, int K, int act, int asel) {
    __shared__ __align__(16) short As[3 * 128 * 32];   // 24 KB
    __shared__ __align__(16) short Bs[3 * 128 * 32];   // 24 KB
    const int tid = threadIdx.x;
    const int lane = tid & 63;
    const int wave = tid >> 6;
    const int wr = (wave >> 1) * 64;
    const int wc = (wave & 1) * 64;
    const int l16 = lane & 15;
    const int quad = lane >> 4;
    const int row0 = blockIdx.x * 128;
    const int col0 = blockIdx.y * 128;
    const int c0 = tid, c1 = tid + 256;
    const int r0 = c0 >> 2, kq0 = (c0 & 3) * 8;
    const int r1 = c1 >> 2, kq1 = (c1 & 3) * 8;
    int ga0 = row0 + r0; if (ga0 >= M) ga0 = M - 1;
    int ga1 = row0 + r1; if (ga1 >= M) ga1 = M - 1;
    const short* Ab = A + (asel ? (col0 & 512) : 0);
    const short* Ap0 = Ab + (size_t)ga0 * lda + kq0;
    const short* Ap1 = Ab + (size_t)ga1 * lda + kq1;
    const short* Bp0 = Bt + (size_t)(col0 + r0) * K + kq0;
    const short* Bp1 = Bt + (size_t)(col0 + r1) * K + kq1;

    f32x4 acc[4][4];
#pragma unroll
    for (int i = 0; i < 4; ++i)
#pragma unroll
        for (int j = 0; j < 4; ++j)
            acc[i][j] = f32x4{0.f, 0.f, 0.f, 0.f};

    const int nsteps = K >> 5;
    // prologue: stage steps 0,1 into buffers 0,1
    gload16(Ap0, &As[c0 * 8]);
    gload16(Ap1, &As[c1 * 8]);
    gload16(Bp0, &Bs[c0 * 8]);
    gload16(Bp1, &Bs[c1 * 8]);
    gload16(Ap0 + 32, &As[4096 + c0 * 8]);
    gload16(Ap1 + 32, &As[4096 + c1 * 8]);
    gload16(Bp0 + 32, &Bs[4096 + c0 * 8]);
    gload16(Bp1 + 32, &Bs[4096 + c1 * 8]);
    int cur = 0, nx2 = 2;
#pragma unroll 1
    for (int ks = 0; ks < nsteps - 1; ++ks) {
        asm volatile("s_waitcnt vmcnt(4)" ::: "memory");
        __builtin_amdgcn_s_barrier();
        if (ks + 2 < nsteps) {
            const int kb = (ks + 2) * 32;
            const int nb = nx2 * 4096;
            gload16(Ap0 + kb, &As[nb + c0 * 8]);
            gload16(Ap1 + kb, &As[nb + c1 * 8]);
            gload16(Bp0 + kb, &Bs[nb + c0 * 8]);
            gload16(Bp1 + kb, &Bs[nb + c1 * 8]);
        }
        const int cb = cur * 4096;
        bf16x8 af[4], bfr[4];
#pragma unroll
        for (int i = 0; i < 4; ++i)
            af[i] = *(const bf16x8*)&As[cb + (wr + i * 16 + l16) * 32 + quad * 8];
#pragma unroll
        for (int j = 0; j < 4; ++j)
            bfr[j] = *(const bf16x8*)&Bs[cb + (wc + j * 16 + l16) * 32 + quad * 8];
#pragma unroll
        for (int i = 0; i < 4; ++i)
#pragma unroll
            for (int j = 0; j < 4; ++j)
                acc[i][j] = __builtin_amdgcn_mfma_f32_16x16x32_bf16(af[i], bfr[j], acc[i][j], 0, 0, 0);
        cur = (cur == 2) ? 0 : cur + 1;
        nx2 = (nx2 == 2) ? 0 : nx2 + 1;
    }
    {   // peeled last step: drain
        asm volatile("s_waitcnt vmcnt(0)" ::: "memory");
        __builtin_amdgcn_s_barrier();
        const int cb = cur * 4096;
        bf16x8 af[4], bfr[4];
#pragma unroll
        for (int i = 0; i < 4; ++i)
            af[i] = *(const bf16x8*)&As[cb + (wr + i * 16 + l16) * 32 + quad * 8];
#pragma unroll
        for (int j = 0; j < 4; ++j)
            bfr[j] = *(const bf16x8*)&Bs[cb + (wc + j * 16 + l16) * 32 + quad * 8];
#pragma unroll
        for (int i = 0; i < 4; ++i)
#pragma unroll
            for (int j = 0; j < 4; ++j)
                acc[i][j] = __builtin_amdgcn_mfma_f32_16x16x32_bf16(af[i], bfr[j], acc[i][j], 0, 0, 0);
    }
#pragma unroll
    for (int i = 0; i < 4; ++i) {
        int rbase = row0 + wr + i * 16 + quad * 4;
#pragma unroll
        for (int j = 0; j < 4; ++j) {
            int c = col0 + wc + j * 16 + l16;
            float bv = bias ? bias[c] : 0.0f;
#pragma unroll
            for (int rg = 0; rg < 4; ++rg) {
                int gr = rbase + rg;
                if (gr < M) {
                    float v = acc[i][j][rg] + bv;
                    if (act) v = gelu1(v);
                    C[(size_t)gr * ldc + c] = (short)f2bf1(v);
                    if (C8) {
                        int r8 = __builtin_amdgcn_cvt_pk_fp8_f32(v, v, 0, false);
                        C8[(size_t)gr * ldc + c] = (unsigned char)(r8 & 0xFF);
                    }
                    if (Cf) Cf[(size_t)gr * ldc + c] = v;
                }
            }
        }
    }
}

// ---------------- qkv GEMM, XCD-swizzled 1D grid, 3-buffer pipeline, split epilogue ---
// Same 2-deep counted-vmcnt pipeline as gemm_bb.
// Output cols: [0,512) q -> qvs (bf16) ; [512,1024) k -> kv8+0 (fp8) ;
// [1024,1536) v -> kv8+512 (fp8) ; [1536,2048) s -> qvs+512 (bf16).

__global__ __launch_bounds__(256) void gemm_qkvs(
    const short* __restrict__ A,      // h_bf [M][512]
    const short* __restrict__ Bt,     // layer weights [2048][512]
    const float* __restrict__ bias,   // [2048]
    short* __restrict__ qvs,          // [M][1024] bf16 (q|s)
    unsigned char* __restrict__ kv8,  // [M][1024] fp8 (k|v)
    int M, int mtiles) {
    const int K = 512;
    const int id = blockIdx.x;
    const int xcd = id & 7;
    const int t = id >> 3;
    const int col_t = t & 15;
    const int row_t = (t >> 4) * 8 + xcd;
    if (row_t >= mtiles) return;
    const int row0 = row_t * 128;
    const int col0 = col_t * 128;
    __shared__ __align__(16) short As[3 * 128 * 32];
    __shared__ __align__(16) short Bs[3 * 128 * 32];
    const int tid = threadIdx.x;
    const int lane = tid & 63;
    const int wave = tid >> 6;
    const int wr = (wave >> 1) * 64;
    const int wc = (wave & 1) * 64;
    const int l16 = lane & 15;
    const int quad = lane >> 4;
    const int c0 = tid, c1 = tid + 256;
    const int r0 = c0 >> 2, kq0 = (c0 & 3) * 8;
    const int r1 = c1 >> 2, kq1 = (c1 & 3) * 8;
    int ga0 = row0 + r0; if (ga0 >= M) ga0 = M - 1;
    int ga1 = row0 + r1; if (ga1 >= M) ga1 = M - 1;
    const short* Ap0 = A + (size_t)ga0 * K + kq0;
    const short* Ap1 = A + (size_t)ga1 * K + kq1;
    const short* Bp0 = Bt + (size_t)(col0 + r0) * K + kq0;
    const short* Bp1 = Bt + (size_t)(col0 + r1) * K + kq1;

    f32x4 acc[4][4];
#pragma unroll
    for (int i = 0; i < 4; ++i)
#pragma unroll
        for (int j = 0; j < 4; ++j)
            acc[i][j] = f32x4{0.f, 0.f, 0.f, 0.f};

    // prologue: stage steps 0,1 into buffers 0,1
    gload16(Ap0, &As[c0 * 8]);
    gload16(Ap1, &As[c1 * 8]);
    gload16(Bp0, &Bs[c0 * 8]);
    gload16(Bp1, &Bs[c1 * 8]);
    gload16(Ap0 + 32, &As[4096 + c0 * 8]);
    gload16(Ap1 + 32, &As[4096 + c1 * 8]);
    gload16(Bp0 + 32, &Bs[4096 + c0 * 8]);
    gload16(Bp1 + 32, &Bs[4096 + c1 * 8]);
    int cur = 0, nx2 = 2;
#pragma unroll 1
    for (int ks = 0; ks < 15; ++ks) {
        asm volatile("s_waitcnt vmcnt(4)" ::: "memory");
        __builtin_amdgcn_s_barrier();
        if (ks + 2 < 16) {
            const int kb = (ks + 2) * 32;
            const int nb = nx2 * 4096;
            gload16(Ap0 + kb, &As[nb + c0 * 8]);
            gload16(Ap1 + kb, &As[nb + c1 * 8]);
            gload16(Bp0 + kb, &Bs[nb + c0 * 8]);
            gload16(Bp1 + kb, &Bs[nb + c1 * 8]);
        }
        const int cb = cur * 4096;
        bf16x8 af[4], bfr[4];
#pragma unroll
        for (int i = 0; i < 4; ++i)
            af[i] = *(const bf16x8*)&As[cb + (wr + i * 16 + l16) * 32 + quad * 8];
#pragma unroll
        for (int j = 0; j < 4; ++j)
            bfr[j] = *(const bf16x8*)&Bs[cb + (wc + j * 16 + l16) * 32 + quad * 8];
#pragma unroll
        for (int i = 0; i < 4; ++i)
#pragma unroll
            for (int j = 0; j < 4; ++j)
                acc[i][j] = __builtin_amdgcn_mfma_f32_16x16x32_bf16(af[i], bfr[j], acc[i][j], 0, 0, 0);
        cur = (cur == 2) ? 0 : cur + 1;
        nx2 = (nx2 == 2) ? 0 : nx2 + 1;
    }
    {   // peeled last step
        asm volatile("s_waitcnt vmcnt(0)" ::: "memory");
        __builtin_amdgcn_s_barrier();
        const int cb = cur * 4096;
        bf16x8 af[4], bfr[4];
#pragma unroll
        for (int i = 0; i < 4; ++i)
            af[i] = *(const bf16x8*)&As[cb + (wr + i * 16 + l16) * 32 + quad * 8];
#pragma unroll
        for (int j = 0; j < 4; ++j)
            bfr[j] = *(const bf16x8*)&Bs[cb + (wc + j * 16 + l16) * 32 + quad * 8];
#pragma unroll
        for (int i = 0; i < 4; ++i)
#pragma unroll
            for (int j = 0; j < 4; ++j)
                acc[i][j] = __builtin_amdgcn_mfma_f32_16x16x32_bf16(af[i], bfr[j], acc[i][j], 0, 0, 0);
    }
#pragma unroll
    for (int i = 0; i < 4; ++i) {
        int rbase = row0 + wr + i * 16 + quad * 4;
#pragma unroll
        for (int j = 0; j < 4; ++j) {
            int c = col0 + wc + j * 16 + l16;
            int sec = c >> 9;           // uniform within a 64-col wave tile
            int cc = c & 511;
            float bv = bias[c];
#pragma unroll
            for (int rg = 0; rg < 4; ++rg) {
                int gr = rbase + rg;
                if (gr < M) {
                    float v = acc[i][j][rg] + bv;
                    if (sec == 1 || sec == 2) {
                        int r8 = __builtin_amdgcn_cvt_pk_fp8_f32(v, v, 0, false);
                        int off = (sec == 1) ? cc : 512 + cc;
                        kv8[(size_t)gr * 1024 + off] = (unsigned char)(r8 & 0xFF);
                    } else {
                        int off = (sec == 0) ? cc : 512 + cc;
                        qvs[(size_t)gr * 1024 + off] = (short)f2bf1(v);
                    }
                }
            }
        }
    }
}

// ---------------- fused gate GEMM v5: + pairscore fusion + final combine -------------
// 128 pairs x 512 cols per block, 512 thr (2Mx4N waves), acc[4][8] (AGPRs).
// Counted s_waitcnt keeps staged loads in flight across raw s_barriers (T3/T4).
// NO setprio (m190/R6). R12: k_pairscore fused — the gate already gathers pair rows
// chunk-by-chunk; add bf16 gathers of tB[i]/zB[j] (same channel schedule) and an
// 8-wide dot per kc, hidden under the latency-bound structure (HBM was 4.7% util).
// vmcnt audit: MU wait 4->6 (standalone retires {Bmu,xn,yn}); AB wait stays 6
// (standalone retires {Bab,tn,zn} — all needed at that point). Tail unchanged.

__global__ __launch_bounds__(512, 2) void gemm_gate(
    const unsigned char* __restrict__ z8,   // [Nn][1024] fp8
    const int* __restrict__ pi, const int* __restrict__ pj, int P,
    const short* __restrict__ Bt,    // gW1^T [512][2048], pre-swizzled
    const float* __restrict__ gb1,
    const float* __restrict__ gW2,
    const float* __restrict__ gb2,
    const short* __restrict__ tB,    // bilinear outputs [Nn][1024] bf16 (syn|ant)
    const short* __restrict__ zB,    // z [Nn][1024] bf16 (syn|ant)
    float* __restrict__ out) {
    __shared__ __align__(16) short Bab[2 * 512 * 32];   // 64 KB
    __shared__ __align__(16) short Bmu[2 * 512 * 32];   // 64 KB
    __shared__ __align__(16) short Asab[128 * 32];      // 8 KB
    __shared__ __align__(16) short Asmu[128 * 32];      // 8 KB
    __shared__ int iArr[128];
    __shared__ int jArr[128];
    __shared__ float rowsum[128];
    __shared__ float dsS[128];
    __shared__ float daS[128];
    const int row0 = blockIdx.x * 128;
    const int tid = threadIdx.x;
    const int lane = tid & 63;
    const int wave = tid >> 6;       // 0..7
    const int wm = wave >> 2;        // 0..1 : 64-row group
    const int wn = wave & 3;         // 0..3 : 128-col group
    const int l16 = lane & 15;
    const int quad = lane >> 4;
    const int arow = tid >> 2;       // 0..127
    const int aslot = tid & 3;
    const int qs = (quad ^ ((l16 >> 1) & 3)) * 8;                       // read swizzle
    const int awoff = arow * 32 + ((aslot ^ ((arow >> 1) & 3)) << 3);   // write swizzle

    if (tid < 128) {
        int p = row0 + tid;
        int ok = (p < P);
        iArr[tid] = ok ? pi[p] : 0;
        jArr[tid] = ok ? pj[p] : 0;
        rowsum[tid] = 0.0f;
    }
    __syncthreads();
    const unsigned char* zi = z8 + (size_t)iArr[arow] * 1024 + aslot * 8;
    const unsigned char* zj = z8 + (size_t)jArr[arow] * 1024 + aslot * 8;
    const short* tbi = tB + (size_t)iArr[arow] * 1024 + aslot * 8;
    const short* zbj = zB + (size_t)jArr[arow] * 1024 + aslot * 8;
    const short* brow = Bt + (size_t)(tid >> 2) * 2048 + (tid & 3) * 8;

    f32x4 acc[4][8];
#pragma unroll
    for (int i = 0; i < 4; ++i)
#pragma unroll
        for (int j = 0; j < 8; ++j)
            acc[i][j] = f32x4{0.f, 0.f, 0.f, 0.f};

    // B source offset (shorts) for k-chunk kc: part = kc>>4, chan = (kc&15)*32
    auto CHB = [](int kc) { return ((kc >> 4) << 10) + ((kc & 15) << 5); };
    // z/t channel offset for k-chunk kc (bytes for z8; shorts for bf16 — same number)
    auto KOFF = [](int kc) { return ((kc >> 4) << 9) + ((kc & 15) << 5); };
    auto STAGE = [&](int kc, int mu, short* buf) {
        const short* src = brow + CHB(kc) + (mu ? 512 : 0);
#pragma unroll
        for (int g = 0; g < 4; ++g)
            gload16(src + (size_t)(g * 128) * 2048, buf + (g * 512 + tid) * 8);
    };
    auto CVT = [&](uint2 xu, uint2 yu, uint4& aa, uint4& am) {
        f32x2 x0 = __builtin_amdgcn_cvt_pk_f32_fp8((int)xu.x, false);
        f32x2 x1 = __builtin_amdgcn_cvt_pk_f32_fp8((int)xu.x, true);
        f32x2 x2 = __builtin_amdgcn_cvt_pk_f32_fp8((int)xu.y, false);
        f32x2 x3 = __builtin_amdgcn_cvt_pk_f32_fp8((int)xu.y, true);
        f32x2 y0 = __builtin_amdgcn_cvt_pk_f32_fp8((int)yu.x, false);
        f32x2 y1 = __builtin_amdgcn_cvt_pk_f32_fp8((int)yu.x, true);
        f32x2 y2 = __builtin_amdgcn_cvt_pk_f32_fp8((int)yu.y, false);
        f32x2 y3 = __builtin_amdgcn_cvt_pk_f32_fp8((int)yu.y, true);
        aa.x = cvt_pk_bf16(fabsf(x0.x - y0.x), fabsf(x0.y - y0.y));
        aa.y = cvt_pk_bf16(fabsf(x1.x - y1.x), fabsf(x1.y - y1.y));
        aa.z = cvt_pk_bf16(fabsf(x2.x - y2.x), fabsf(x2.y - y2.y));
        aa.w = cvt_pk_bf16(fabsf(x3.x - y3.x), fabsf(x3.y - y3.y));
        am.x = cvt_pk_bf16(x0.x * y0.x, x0.y * y0.y);
        am.y = cvt_pk_bf16(x1.x * y1.x, x1.y * y1.y);
        am.z = cvt_pk_bf16(x2.x * y2.x, x2.y * y2.y);
        am.w = cvt_pk_bf16(x3.x * y3.x, x3.y * y3.y);
    };
    auto DOT8 = [&](uint4 tv, uint4 zv) -> float {
        float2 t0 = bfp2(tv.x), t1 = bfp2(tv.y), t2 = bfp2(tv.z), t3 = bfp2(tv.w);
        float2 p0 = bfp2(zv.x), p1 = bfp2(zv.y), p2 = bfp2(zv.z), p3 = bfp2(zv.w);
        return t0.x * p0.x + t0.y * p0.y + t1.x * p1.x + t1.y * p1.y +
               t2.x * p2.x + t2.y * p2.y + t3.x * p3.x + t3.y * p3.y;
    };
    auto MFMA_PHASE = [&](const short* As, const short* Bp) {
        bf16x8 af[4];
#pragma unroll
        for (int i = 0; i < 4; ++i)
            af[i] = *(const bf16x8*)&As[(wm * 64 + i * 16 + l16) * 32 + qs];
#pragma unroll
        for (int j = 0; j < 8; ++j) {
            bf16x8 bf = *(const bf16x8*)&Bp[(wn * 128 + j * 16 + l16) * 32 + qs];
#pragma unroll
            for (int i = 0; i < 4; ++i)
                acc[i][j] = __builtin_amdgcn_mfma_f32_16x16x32_bf16(af[i], bf, acc[i][j], 0, 0, 0);
        }
    };

    // ---- prologue: stage AB(0), load z(0) + t/z-bf16(0), cvt ----
    STAGE(0, 0, Bab);
    uint2 xu = *(const uint2*)zi;
    uint2 yu = *(const uint2*)zj;
    uint4 tu = *(const uint4*)tbi;      // chunk 0
    uint4 zu = *(const uint4*)zbj;
    uint4 aa, am, am_hold;
    CVT(xu, yu, aa, am);
    *(uint4*)&Asab[awoff] = aa;
    am_hold = am;
    float ds = 0.f, da = 0.f;

#pragma unroll 1
    for (int kc = 0; kc < 31; ++kc) {
        const int cur = kc & 1;
        // ---- AB sub-phase ----
        STAGE(kc, 1, Bmu + cur * 16384);
        uint2 xn = *(const uint2*)(zi + KOFF(kc + 1));
        uint2 yn = *(const uint2*)(zj + KOFF(kc + 1));
        {   // pairscore dot for chunk kc (tu,zu loaded last MU / prologue)
            float pd = DOT8(tu, zu);
            if (kc < 16) ds += pd; else da += pd;
        }
        asm volatile("s_waitcnt vmcnt(6) lgkmcnt(0)" ::: "memory");
        __builtin_amdgcn_s_barrier();
        MFMA_PHASE(Asab, Bab + cur * 16384);
        *(uint4*)&Asmu[awoff] = am_hold;          // post-section write (for mu of this kc)
        // ---- MU sub-phase ----
        STAGE(kc + 1, 0, Bab + (cur ^ 1) * 16384);
        tu = *(const uint4*)(tbi + KOFF(kc + 1));  // chunk kc+1
        zu = *(const uint4*)(zbj + KOFF(kc + 1));
        CVT(xn, yn, aa, am);                      // implicit z-wait retires Bmu[cur]
        asm volatile("s_waitcnt vmcnt(6) lgkmcnt(0)" ::: "memory");
        __builtin_amdgcn_s_barrier();
        MFMA_PHASE(Asmu, Bmu + cur * 16384);
        *(uint4*)&Asab[awoff] = aa;               // post-section write (for ab of kc+1)
        am_hold = am;
    }
    // ---- tail kc = 31 (cur = 1) ----
    STAGE(31, 1, Bmu + 16384);
    da += DOT8(tu, zu);                           // chunk 31 (ant half)
    asm volatile("s_waitcnt vmcnt(4) lgkmcnt(0)" ::: "memory");
    __builtin_amdgcn_s_barrier();
    MFMA_PHASE(Asab, Bab + 16384);
    *(uint4*)&Asmu[awoff] = am_hold;
    asm volatile("s_waitcnt vmcnt(0) lgkmcnt(0)" ::: "memory");
    __builtin_amdgcn_s_barrier();
    MFMA_PHASE(Asmu, Bmu + 16384);

    // ---- pairscore reduce across the 4 aslot lanes of each row ----
    ds += __shfl_xor(ds, 1);
    ds += __shfl_xor(ds, 2);
    da += __shfl_xor(da, 1);
    da += __shfl_xor(da, 2);
    if (aslot == 0) { dsS[arow] = ds; daS[arow] = da; }

    // ---- epilogue: fused gelu + gW2 dot, per-row reduce, sigmoid combine ----
#pragma unroll
    for (int i = 0; i < 4; ++i) {
#pragma unroll
        for (int rg = 0; rg < 4; ++rg) {
            float partial = 0.f;
#pragma unroll
            for (int j = 0; j < 8; ++j) {
                int cc = wn * 128 + j * 16 + l16;
                partial += gelu1(acc[i][j][rg] + gb1[cc]) * gW2[cc];
            }
            partial += __shfl_xor(partial, 1);
            partial += __shfl_xor(partial, 2);
            partial += __shfl_xor(partial, 4);
            partial += __shfl_xor(partial, 8);
            if (l16 == 0)
                atomicAdd(&rowsum[wm * 64 + i * 16 + quad * 4 + rg], partial);
        }
    }
    __syncthreads();
    if (tid < 128) {
        int p = row0 + tid;
        if (p < P) {
            float s = 1.0f / (1.0f + __expf(-(rowsum[tid] + gb2[0])));
            out[p] = s * daS[tid] - (1.0f - s) * dsS[tid];
        }
    }
}

// ---------------- fused per-layer attention: single-pass, fp8 k AND v gather ----------
// qvs bf16 [Nn][1024] (q|s), kv8 fp8 [Nn][1024] (k|v). Per edge: 8B k + 8B v per lane.
// Edge loop unrolled 8-deep (R7/R11): scattered kv8 loads issued up front for MLP;
// sequential online-softmax order preserved (numerics identical).

__global__ __launch_bounds__(256) void k_attn(const short* __restrict__ qvs,
                                              const unsigned char* __restrict__ kv8,
                                              const int* __restrict__ srcS,
                                              const int* __restrict__ offs,
                                              float* __restrict__ h,
                                              short* __restrict__ h_bf,
                                              const float* __restrict__ lng,
                                              const float* __restrict__ lnb, int Nn) {
    const int tid = threadIdx.x;
    const int lane = tid & 63;
    const int wv = tid >> 6;
    const int n = blockIdx.x * 4 + wv;
    if (n >= Nn) return;
    const int st = offs[n], en = offs[n + 1];
    const size_t chOff = (size_t)lane * 8;

    uint4 qv = *(const uint4*)(qvs + (size_t)n * 1024 + chOff);
    float2 q0 = bfp2(qv.x), q1 = bfp2(qv.y), q2 = bfp2(qv.z), q3 = bfp2(qv.w);
    float acc[8];
#pragma unroll
    for (int i = 0; i < 8; ++i) acc[i] = 0.f;
    float m_l = -3.4e38f, l_l = 0.f;

    auto PROC = [&](uint2 kq, uint2 vq) {
        f32x2 k0 = __builtin_amdgcn_cvt_pk_f32_fp8((int)kq.x, false);
        f32x2 k1 = __builtin_amdgcn_cvt_pk_f32_fp8((int)kq.x, true);
        f32x2 k2 = __builtin_amdgcn_cvt_pk_f32_fp8((int)kq.y, false);
        f32x2 k3 = __builtin_amdgcn_cvt_pk_f32_fp8((int)kq.y, true);
        float d = q0.x * k0.x + q0.y * k0.y + q1.x * k1.x + q1.y * k1.y +
                  q2.x * k2.x + q2.y * k2.y + q3.x * k3.x + q3.y * k3.y;
        d += __shfl_xor(d, 1);
        d += __shfl_xor(d, 2);
        d += __shfl_xor(d, 4);
        d += __shfl_xor(d, 8);
        float lg = d * 0.08838834764831845f;
        float m_new = fmaxf(m_l, lg);
        float sc = __expf(m_l - m_new);
        float p = __expf(lg - m_new);
        l_l = l_l * sc + p;
        m_l = m_new;
        f32x2 v0 = __builtin_amdgcn_cvt_pk_f32_fp8((int)vq.x, false);
        f32x2 v1 = __builtin_amdgcn_cvt_pk_f32_fp8((int)vq.x, true);
        f32x2 v2 = __builtin_amdgcn_cvt_pk_f32_fp8((int)vq.y, false);
        f32x2 v3 = __builtin_amdgcn_cvt_pk_f32_fp8((int)vq.y, true);
        acc[0] = acc[0] * sc + p * v0.x; acc[1] = acc[1] * sc + p * v0.y;
        acc[2] = acc[2] * sc + p * v1.x; acc[3] = acc[3] * sc + p * v1.y;
        acc[4] = acc[4] * sc + p * v2.x; acc[5] = acc[5] * sc + p * v2.y;
        acc[6] = acc[6] * sc + p * v3.x; acc[7] = acc[7] * sc + p * v3.y;
    };

    for (int e0 = st; e0 < en; e0 += 64) {
        int cnt = min(64, en - e0);
        int myS = (lane < cnt) ? srcS[e0 + lane] : 0;
        int ei = 0;
        for (; ei + 8 <= cnt; ei += 8) {
            const unsigned char* rp[8];
#pragma unroll
            for (int u = 0; u < 8; ++u) {
                int s = __shfl(myS, ei + u);
                rp[u] = kv8 + (size_t)s * 1024 + chOff;
            }
            uint2 kk[8], vv[8];
#pragma unroll
            for (int u = 0; u < 8; ++u) {
                kk[u] = *(const uint2*)rp[u];
                vv[u] = *(const uint2*)(rp[u] + 512);
            }
#pragma unroll
            for (int u = 0; u < 8; ++u) PROC(kk[u], vv[u]);
        }
        for (; ei < cnt; ++ei) {
            int s = __shfl(myS, ei);
            const unsigned char* srow = kv8 + (size_t)s * 1024 + chOff;
            uint2 kq = *(const uint2*)srow;
            uint2 vq = *(const uint2*)(srow + 512);
            PROC(kq, vq);
        }
    }
    float rinv = (en > st) ? 1.0f / l_l : 0.f;
    uint4 su = *(const uint4*)(qvs + (size_t)n * 1024 + 512 + chOff);
    float2 s0 = bfp2(su.x), s1 = bfp2(su.y), s2 = bfp2(su.z), s3 = bfp2(su.w);
    float sv[8] = {s0.x, s0.y, s1.x, s1.y, s2.x, s2.y, s3.x, s3.y};
    const float* hp = h + (size_t)n * 512 + chOff;
    float4 h0 = *(const float4*)hp;
    float4 h1 = *(const float4*)(hp + 4);
    float hv[8] = {h0.x, h0.y, h0.z, h0.w, h1.x, h1.y, h1.z, h1.w};
    float r[8];
    float sum = 0.f, ssq = 0.f;
#pragma unroll
    for (int i = 0; i < 8; ++i) {
        r[i] = hv[i] + gelu1(acc[i] * rinv + sv[i]);
        sum += r[i];
        ssq += r[i] * r[i];
    }
    for (int o = 32; o; o >>= 1) {
        sum += __shfl_xor(sum, o);
        ssq += __shfl_xor(ssq, o);
    }
    float mean = sum * (1.0f / 512.0f);
    float var = ssq * (1.0f / 512.0f) - mean * mean;
    float inv = rsqrtf(var + 1e-5f);
    const float* gp = lng + chOff;
    const float* bp = lnb + chOff;
    float4 g0 = *(const float4*)gp, g1 = *(const float4*)(gp + 4);
    float4 b0 = *(const float4*)bp, b1 = *(const float4*)(bp + 4);
    float ga[8] = {g0.x, g0.y, g0.z, g0.w, g1.x, g1.y, g1.z, g1.w};
    float ba[8] = {b0.x, b0.y, b0.z, b0.w, b1.x, b1.y, b1.z, b1.w};
    float o8[8];
#pragma unroll
    for (int i = 0; i < 8; ++i) o8[i] = (r[i] - mean) * inv * ga[i] + ba[i];
    float* hw = h + (size_t)n * 512 + chOff;
    *(float4*)hw = make_float4(o8[0], o8[1], o8[2], o8[3]);
    *(float4*)(hw + 4) = make_float4(o8[4], o8[5], o8[6], o8[7]);
    uint4 ob;
    ob.x = f2bf2(o8[0], o8[1]);
    ob.y = f2bf2(o8[2], o8[3]);
    ob.z = f2bf2(o8[4], o8[5]);
    ob.w = f2bf2(o8[6], o8[7]);
    *(uint4*)(h_bf + (size_t)n * 512 + chOff) = ob;
}

// ---------------- host ----------------

extern "C" void kernel_launch(void* const* d_in, const int* in_sizes, int n_in,
                              void* d_out, int out_size, void* d_ws, size_t ws_size,
                              hipStream_t stream) {
    const float* x = (const float*)d_in[0];
    const int* ei = (const int*)d_in[1];
    const int* pe = (const int*)d_in[2];
    const float* mixer_W = (const float*)d_in[3];
    const float* mixer_b = (const float*)d_in[4];
    const float* Wq = (const float*)d_in[5];
    const float* bq = (const float*)d_in[6];
    const float* Wk = (const float*)d_in[7];
    const float* bk = (const float*)d_in[8];
    const float* Wv = (const float*)d_in[9];
    const float* bv = (const float*)d_in[10];
    const float* Ws = (const float*)d_in[11];
    const float* bs = (const float*)d_in[12];
    const float* ln_g = (const float*)d_in[13];
    const float* ln_b = (const float*)d_in[14];
    const float* syn_W = (const float*)d_in[15];
    const float* syn_b = (const float*)d_in[16];
    const float* ant_W = (const float*)d_in[17];
    const float* ant_b = (const float*)d_in[18];
    const float* W_syn = (const float*)d_in[19];
    const float* W_ant = (const float*)d_in[20];
    const float* gW1 = (const float*)d_in[21];
    const float* gb1 = (const float*)d_in[22];
    const float* gW2 = (const float*)d_in[23];
    const float* gb2 = (const float*)d_in[24];
    float* out = (float*)d_out;

    const int Nn = in_sizes[0] / 768;  // 20000
    const int E = in_sizes[1] / 2;     // 320000
    const int P = in_sizes[2] / 2;     // 100000

    char* w = (char*)d_ws;
    auto alloc = [&](size_t bytes) -> char* {
        char* p = w;
        w += (bytes + 255) & ~(size_t)255;
        return p;
    };
    float* h = (float*)alloc((size_t)Nn * 512 * 4);
    short* h_bf = (short*)alloc((size_t)Nn * 512 * 2);
    // union region U: pre-mixer = x_bf [Nn][768] bf16 ; during layers = qvs [Nn][1024]
    // bf16 (q|s) + kv8 [Nn][1024] fp8 (k|v) ; after layers = zB | tB (bf16)
    char* U = alloc((size_t)Nn * 2048 * 2);
    short* x_bf = (short*)U;                      // 30.7 MB < |U|; dead after mixer
    short* qvs = (short*)U;
    unsigned char* kv8 = (unsigned char*)(U + (size_t)Nn * 1024 * 2);
    short* zB = (short*)U;
    short* tB = (short*)(U + (size_t)Nn * 1024 * 2);
    unsigned char* z8 = (unsigned char*)alloc((size_t)Nn * 1024);   // fp8 z copy, 20 MB
    int* srcS = (int*)alloc((size_t)E * 4);
    int* hist = (int*)alloc((size_t)Nn * 2 * 4);
    int* cursor = hist + Nn;
    int* offs = (int*)alloc((size_t)(Nn + 1) * 4);
    short* mixWt = (short*)alloc((size_t)512 * 768 * 2);
    short* wcat = (short*)alloc((size_t)L_LAYERS * 2048 * 512 * 2);
    short* dualWt = (short*)alloc((size_t)1024 * 512 * 2);
    short* bilWt = (short*)alloc((size_t)1024 * 512 * 2);
    short* gw1t = (short*)alloc((size_t)512 * 2048 * 2);
    float* bcat = (float*)alloc((size_t)L_LAYERS * 2048 * 4);
    float* bdual = (float*)alloc((size_t)1024 * 4);

    k_zero<<<(2 * Nn + 255) / 256, 256, 0, stream>>>(hist, 2 * Nn);
    k_hist<<<(E + 255) / 256, 256, 0, stream>>>(ei + E, hist, E);
    k_scan<<<1, 1024, 0, stream>>>(hist, offs, Nn);
    k_scatter<<<(E + 255) / 256, 256, 0, stream>>>(ei, ei + E, offs, cursor, srcS, E);

    k_wcat<<<(L_LAYERS * 2048 * 512) / 256, 256, 0, stream>>>(Wq, Wk, Wv, Ws, wcat);
    k_tr<<<dim3(3, 512), 256, 0, stream>>>(mixer_W, mixWt, 768, 512, 0);
    k_tr<<<dim3(2, 512), 256, 0, stream>>>(syn_W, dualWt, 512, 512, 0);
    k_tr<<<dim3(2, 512), 256, 0, stream>>>(ant_W, dualWt + 512 * 512, 512, 512, 0);
    k_tr<<<dim3(2, 512), 256, 0, stream>>>(W_syn, bilWt, 512, 512, 0);
    k_tr<<<dim3(2, 512), 256, 0, stream>>>(W_ant, bilWt + 512 * 512, 512, 512, 0);
    k_tr<<<dim3(8, 512), 256, 0, stream>>>(gW1, gw1t, 2048, 512, 1);   // pre-swizzled for gemm_gate
    k_bcat<<<48, 256, 0, stream>>>(bq, bk, bv, bs, bcat);
    k_bdual<<<4, 256, 0, stream>>>(syn_b, ant_b, bdual);

    const int mtiles = (Nn + 127) / 128;  // 157
    // mixer: x -> bf16 once, then gload_lds GEMM (replaces VALU-bound gemm_a32)
    k_cvt<<<(Nn * 768 / 8 + 255) / 256, 256, 0, stream>>>(x, x_bf, Nn * 768 / 8);
    gemm_bb<<<dim3(mtiles, 4), 256, 0, stream>>>(x_bf, 768, mixWt, mixer_b, h_bf,
                                                 nullptr, h, 512, Nn, 512, 768, 1, 0);

    // XCD-swizzled 1D grid: ceil(mtiles/8)*8 row slots x 16 col tiles
    const int qk_grid = ((mtiles + 7) / 8) * 8 * 16;   // 2560
    for (int l = 0; l < L_LAYERS; ++l) {
        gemm_qkvs<<<qk_grid, 256, 0, stream>>>(h_bf, wcat + (size_t)l * 2048 * 512,
                                               bcat + l * 2048, qvs, kv8, Nn, mtiles);
        k_attn<<<(Nn + 3) / 4, 256, 0, stream>>>(qvs, kv8, srcS, offs, h, h_bf,
                                                 ln_g + l * 512, ln_b + l * 512, Nn);
    }

    // z = gelu(h @ [syn_W|ant_W] + b) -> zB bf16 + z8 fp8
    gemm_bb<<<dim3(mtiles, 8), 256, 0, stream>>>(h_bf, 512, dualWt, bdual, zB, z8,
                                                 nullptr, 1024, Nn, 1024, 512, 1, 0);
    // merged bilinear: tB[:,0:512] = zB[:,0:512]@W_syn^T ; tB[:,512:] = zB[:,512:]@W_ant^T
    gemm_bb<<<dim3(mtiles, 8), 256, 0, stream>>>(zB, 1024, bilWt, nullptr, tB, nullptr,
                                                 nullptr, 1024, Nn, 1024, 512, 0, 1);

    // gate + pairscore + final combine, all fused
    const int ptiles2 = (P + 127) / 128;               // 782
    gemm_gate<<<ptiles2, 512, 0, stream>>>(z8, pe, pe + P, P, gw1t, gb1, gW2,
                                           gb2, tB, zB, out);
}

// Round 13
// 1578.734 us; speedup vs baseline: 1.0235x; 1.0124x over previous
//
#include <hip/hip_runtime.h>
#include <cstdint>

#define L_LAYERS 6

typedef __attribute__((ext_vector_type(8))) short bf16x8;
typedef __attribute__((ext_vector_type(4))) float f32x4;
typedef __attribute__((ext_vector_type(2))) float f32x2;

__device__ __forceinline__ float gelu1(float v) {
    return 0.5f * v * (1.0f + erff(v * 0.7071067811865475f));
}

__device__ __forceinline__ unsigned int f2bf2(float a, float b) {
    union { float f; unsigned u; } x, y;
    x.f = a; y.f = b;
    unsigned lo = (x.u + 0x7FFFu + ((x.u >> 16) & 1u)) >> 16;
    unsigned hi = (y.u + 0x7FFFu + ((y.u >> 16) & 1u)) & 0xFFFF0000u;
    return lo | hi;
}

__device__ __forceinline__ unsigned short f2bf1(float a) {
    union { float f; unsigned u; } x;
    x.f = a;
    return (unsigned short)((x.u + 0x7FFFu + ((x.u >> 16) & 1u)) >> 16);
}

// single-instruction RNE pack of two f32 -> packed bf16x2 (same rounding as f2bf2)
__device__ __forceinline__ unsigned cvt_pk_bf16(float lo, float hi) {
    unsigned r;
    asm("v_cvt_pk_bf16_f32 %0, %1, %2" : "=v"(r) : "v"(lo), "v"(hi));
    return r;
}

__device__ __forceinline__ float2 bfp2(unsigned u) {
    union { unsigned u; float f; } a, b;
    a.u = u << 16;
    b.u = u & 0xFFFF0000u;
    return make_float2(a.f, b.f);
}

// async global->LDS, 16 bytes per lane (dest = wave-uniform base + lane*16)
__device__ __forceinline__ void gload16(const void* g, void* l) {
    __builtin_amdgcn_global_load_lds(
        (const __attribute__((address_space(1))) void*)g,
        (__attribute__((address_space(3))) void*)l, 16, 0, 0);
}

// ---------------- utility ----------------

__global__ void k_zero(int* __restrict__ p, int n) {
    int i = blockIdx.x * 256 + threadIdx.x;
    if (i < n) p[i] = 0;
}

// f32 -> bf16 bulk convert (8 elems/thread, fully vectorized; G13)
__global__ void k_cvt(const float* __restrict__ x, short* __restrict__ xb, int n8) {
    int i = blockIdx.x * 256 + threadIdx.x;
    if (i < n8) {
        const float4* p = (const float4*)(x + (size_t)i * 8);
        float4 a0 = p[0], a1 = p[1];
        uint4 o;
        o.x = f2bf2(a0.x, a0.y);
        o.y = f2bf2(a0.z, a0.w);
        o.z = f2bf2(a1.x, a1.y);
        o.w = f2bf2(a1.z, a1.w);
        *(uint4*)(xb + (size_t)i * 8) = o;
    }
}

// ---------------- edge sorting (counting sort by dst) ----------------

__global__ void k_hist(const int* __restrict__ dst, int* __restrict__ hist, int E) {
    int e = blockIdx.x * 256 + threadIdx.x;
    if (e < E) atomicAdd(&hist[dst[e]], 1);
}

__global__ __launch_bounds__(1024) void k_scan(const int* __restrict__ hist,
                                               int* __restrict__ off, int n) {
    __shared__ int buf[1024];
    __shared__ int carry;
    int tid = threadIdx.x;
    if (tid == 0) carry = 0;
    __syncthreads();
    for (int base = 0; base < n; base += 1024) {
        int v = (base + tid < n) ? hist[base + tid] : 0;
        buf[tid] = v;
        __syncthreads();
        int x = v;
        for (int o = 1; o < 1024; o <<= 1) {
            int t = (tid >= o) ? buf[tid - o] : 0;
            __syncthreads();
            x += t;
            buf[tid] = x;
            __syncthreads();
        }
        int c = carry;
        if (base + tid < n) off[base + tid] = c + x - v;   // exclusive
        __syncthreads();
        if (tid == 1023) carry = c + buf[1023];
        __syncthreads();
    }
    if (tid == 0) off[n] = carry;
}

__global__ void k_scatter(const int* __restrict__ src, const int* __restrict__ dst,
                          const int* __restrict__ off, int* __restrict__ cursor,
                          int* __restrict__ srcS, int E) {
    int e = blockIdx.x * 256 + threadIdx.x;
    if (e < E) {
        int d = dst[e];
        int pos = off[d] + atomicAdd(&cursor[d], 1);
        srcS[pos] = src[e];
    }
}

// ---------------- weight prep (transpose + cvt to bf16) ----------------

__global__ void k_wcat(const float* __restrict__ Wq, const float* __restrict__ Wk,
                       const float* __restrict__ Wv, const float* __restrict__ Ws,
                       short* __restrict__ Wt) {
    int idx = blockIdx.x * 256 + threadIdx.x;   // l*2^20 + n*512 + k
    int k = idx & 511;
    int nf = (idx >> 9) & 2047;
    int l = idx >> 20;
    int sel = nf >> 9, nn = nf & 511;
    const float* W = (sel == 0) ? Wq : (sel == 1) ? Wk : (sel == 2) ? Wv : Ws;
    float v = W[((size_t)l * 512 + k) * 512 + nn];
    Wt[idx] = (short)f2bf1(v);
}

// swz=1: XOR-permute 16B sub-blocks within each 64B k-chunk by ((n>>1)&3) so that
// linear global_load_lds staging + swizzled ds_read in gemm_gate is conflict-free.
__global__ void k_tr(const float* __restrict__ W, short* __restrict__ Wt, int K, int N,
                     int swz) {
    int k = blockIdx.x * 256 + threadIdx.x;
    int n = blockIdx.y;
    if (k < K) {
        int kk = k;
        if (swz) kk = (k & ~31) | (((((k >> 3) & 3) ^ ((n >> 1) & 3))) << 3) | (k & 7);
        Wt[(size_t)n * K + kk] = (short)f2bf1(W[(size_t)k * N + n]);
    }
}

__global__ void k_bcat(const float* __restrict__ bq, const float* __restrict__ bk,
                       const float* __restrict__ bv, const float* __restrict__ bs,
                       float* __restrict__ bcat) {
    int idx = blockIdx.x * 256 + threadIdx.x;
    if (idx >= L_LAYERS * 2048) return;
    int l = idx >> 11, n = idx & 2047;
    int sel = n >> 9, nn = n & 511;
    const float* b = (sel == 0) ? bq : (sel == 1) ? bk : (sel == 2) ? bv : bs;
    bcat[idx] = b[l * 512 + nn];
}

__global__ void k_bdual(const float* __restrict__ sb, const float* __restrict__ ab,
                        float* __restrict__ bd) {
    int idx = blockIdx.x * 256 + threadIdx.x;
    if (idx < 1024) bd[idx] = (idx < 512) ? sb[idx] : ab[idx - 512];
}

// ---------------- GEMM: A bf16, B bf16, 3-buffer 2-deep pipelined staging -------------
// Stage k+2 issued right after barrier k (2 compute iterations of cover), counted
// vmcnt(4) at top retires exactly stage k. NO setprio (m190/R6). Tail peeled.
// Requires K >= 96 (>=3 steps); call sites use K=512/768.
// Optional outputs: C8 (fp8 e4m3 copy), Cf (f32 copy, for the mixer's residual h).
// asel=1: block-diagonal mode for the merged bilinear GEMM — A column base is
// (col0 & 512), so C[:,0:512] = A[:,0:512]@Bt[0:512] and C[:,512:] = A[:,512:]@Bt[512:].

__global__ __launch_bounds__(256) void gemm_bb(
    const short* __restrict__ A, int lda,
    const short* __restrict__ Bt,
    const float* __restrict__ bias,
    short* __restrict__ C, unsigned char* __restrict__ C8, float* __restrict__ Cf,
    int ldc, int M, int N, int K, int act, int asel) {
    __shared__ __align__(16) short As[3 * 128 * 32];   // 24 KB
    __shared__ __align__(16) short Bs[3 * 128 * 32];   // 24 KB
    const int tid = threadIdx.x;
    const int lane = tid & 63;
    const int wave = tid >> 6;
    const int wr = (wave >> 1) * 64;
    const int wc = (wave & 1) * 64;
    const int l16 = lane & 15;
    const int quad = lane >> 4;
    const int row0 = blockIdx.x * 128;
    const int col0 = blockIdx.y * 128;
    const int c0 = tid, c1 = tid + 256;
    const int r0 = c0 >> 2, kq0 = (c0 & 3) * 8;
    const int r1 = c1 >> 2, kq1 = (c1 & 3) * 8;
    int ga0 = row0 + r0; if (ga0 >= M) ga0 = M - 1;
    int ga1 = row0 + r1; if (ga1 >= M) ga1 = M - 1;
    const short* Ab = A + (asel ? (col0 & 512) : 0);
    const short* Ap0 = Ab + (size_t)ga0 * lda + kq0;
    const short* Ap1 = Ab + (size_t)ga1 * lda + kq1;
    const short* Bp0 = Bt + (size_t)(col0 + r0) * K + kq0;
    const short* Bp1 = Bt + (size_t)(col0 + r1) * K + kq1;

    f32x4 acc[4][4];
#pragma unroll
    for (int i = 0; i < 4; ++i)
#pragma unroll
        for (int j = 0; j < 4; ++j)
            acc[i][j] = f32x4{0.f, 0.f, 0.f, 0.f};

    const int nsteps = K >> 5;
    // prologue: stage steps 0,1 into buffers 0,1
    gload16(Ap0, &As[c0 * 8]);
    gload16(Ap1, &As[c1 * 8]);
    gload16(Bp0, &Bs[c0 * 8]);
    gload16(Bp1, &Bs[c1 * 8]);
    gload16(Ap0 + 32, &As[4096 + c0 * 8]);
    gload16(Ap1 + 32, &As[4096 + c1 * 8]);
    gload16(Bp0 + 32, &Bs[4096 + c0 * 8]);
    gload16(Bp1 + 32, &Bs[4096 + c1 * 8]);
    int cur = 0, nx2 = 2;
#pragma unroll 1
    for (int ks = 0; ks < nsteps - 1; ++ks) {
        asm volatile("s_waitcnt vmcnt(4)" ::: "memory");
        __builtin_amdgcn_s_barrier();
        if (ks + 2 < nsteps) {
            const int kb = (ks + 2) * 32;
            const int nb = nx2 * 4096;
            gload16(Ap0 + kb, &As[nb + c0 * 8]);
            gload16(Ap1 + kb, &As[nb + c1 * 8]);
            gload16(Bp0 + kb, &Bs[nb + c0 * 8]);
            gload16(Bp1 + kb, &Bs[nb + c1 * 8]);
        }
        const int cb = cur * 4096;
        bf16x8 af[4], bfr[4];
#pragma unroll
        for (int i = 0; i < 4; ++i)
            af[i] = *(const bf16x8*)&As[cb + (wr + i * 16 + l16) * 32 + quad * 8];
#pragma unroll
        for (int j = 0; j < 4; ++j)
            bfr[j] = *(const bf16x8*)&Bs[cb + (wc + j * 16 + l16) * 32 + quad * 8];
#pragma unroll
        for (int i = 0; i < 4; ++i)
#pragma unroll
            for (int j = 0; j < 4; ++j)
                acc[i][j] = __builtin_amdgcn_mfma_f32_16x16x32_bf16(af[i], bfr[j], acc[i][j], 0, 0, 0);
        cur = (cur == 2) ? 0 : cur + 1;
        nx2 = (nx2 == 2) ? 0 : nx2 + 1;
    }
    {   // peeled last step: drain
        asm volatile("s_waitcnt vmcnt(0)" ::: "memory");
        __builtin_amdgcn_s_barrier();
        const int cb = cur * 4096;
        bf16x8 af[4], bfr[4];
#pragma unroll
        for (int i = 0; i < 4; ++i)
            af[i] = *(const bf16x8*)&As[cb + (wr + i * 16 + l16) * 32 + quad * 8];
#pragma unroll
        for (int j = 0; j < 4; ++j)
            bfr[j] = *(const bf16x8*)&Bs[cb + (wc + j * 16 + l16) * 32 + quad * 8];
#pragma unroll
        for (int i = 0; i < 4; ++i)
#pragma unroll
            for (int j = 0; j < 4; ++j)
                acc[i][j] = __builtin_amdgcn_mfma_f32_16x16x32_bf16(af[i], bfr[j], acc[i][j], 0, 0, 0);
    }
#pragma unroll
    for (int i = 0; i < 4; ++i) {
        int rbase = row0 + wr + i * 16 + quad * 4;
#pragma unroll
        for (int j = 0; j < 4; ++j) {
            int c = col0 + wc + j * 16 + l16;
            float bv = bias ? bias[c] : 0.0f;
#pragma unroll
            for (int rg = 0; rg < 4; ++rg) {
                int gr = rbase + rg;
                if (gr < M) {
                    float v = acc[i][j][rg] + bv;
                    if (act) v = gelu1(v);
                    C[(size_t)gr * ldc + c] = (short)f2bf1(v);
                    if (C8) {
                        int r8 = __builtin_amdgcn_cvt_pk_fp8_f32(v, v, 0, false);
                        C8[(size_t)gr * ldc + c] = (unsigned char)(r8 & 0xFF);
                    }
                    if (Cf) Cf[(size_t)gr * ldc + c] = v;
                }
            }
        }
    }
}

// ---------------- qkv GEMM, XCD-swizzled 1D grid, 3-buffer pipeline, split epilogue ---
// Same 2-deep counted-vmcnt pipeline as gemm_bb.
// Output cols: [0,512) q -> qvs (bf16) ; [512,1024) k -> kv8+0 (fp8) ;
// [1024,1536) v -> kv8+512 (fp8) ; [1536,2048) s -> qvs+512 (bf16).

__global__ __launch_bounds__(256) void gemm_qkvs(
    const short* __restrict__ A,      // h_bf [M][512]
    const short* __restrict__ Bt,     // layer weights [2048][512]
    const float* __restrict__ bias,   // [2048]
    short* __restrict__ qvs,          // [M][1024] bf16 (q|s)
    unsigned char* __restrict__ kv8,  // [M][1024] fp8 (k|v)
    int M, int mtiles) {
    const int K = 512;
    const int id = blockIdx.x;
    const int xcd = id & 7;
    const int t = id >> 3;
    const int col_t = t & 15;
    const int row_t = (t >> 4) * 8 + xcd;
    if (row_t >= mtiles) return;
    const int row0 = row_t * 128;
    const int col0 = col_t * 128;
    __shared__ __align__(16) short As[3 * 128 * 32];
    __shared__ __align__(16) short Bs[3 * 128 * 32];
    const int tid = threadIdx.x;
    const int lane = tid & 63;
    const int wave = tid >> 6;
    const int wr = (wave >> 1) * 64;
    const int wc = (wave & 1) * 64;
    const int l16 = lane & 15;
    const int quad = lane >> 4;
    const int c0 = tid, c1 = tid + 256;
    const int r0 = c0 >> 2, kq0 = (c0 & 3) * 8;
    const int r1 = c1 >> 2, kq1 = (c1 & 3) * 8;
    int ga0 = row0 + r0; if (ga0 >= M) ga0 = M - 1;
    int ga1 = row0 + r1; if (ga1 >= M) ga1 = M - 1;
    const short* Ap0 = A + (size_t)ga0 * K + kq0;
    const short* Ap1 = A + (size_t)ga1 * K + kq1;
    const short* Bp0 = Bt + (size_t)(col0 + r0) * K + kq0;
    const short* Bp1 = Bt + (size_t)(col0 + r1) * K + kq1;

    f32x4 acc[4][4];
#pragma unroll
    for (int i = 0; i < 4; ++i)
#pragma unroll
        for (int j = 0; j < 4; ++j)
            acc[i][j] = f32x4{0.f, 0.f, 0.f, 0.f};

    // prologue: stage steps 0,1 into buffers 0,1
    gload16(Ap0, &As[c0 * 8]);
    gload16(Ap1, &As[c1 * 8]);
    gload16(Bp0, &Bs[c0 * 8]);
    gload16(Bp1, &Bs[c1 * 8]);
    gload16(Ap0 + 32, &As[4096 + c0 * 8]);
    gload16(Ap1 + 32, &As[4096 + c1 * 8]);
    gload16(Bp0 + 32, &Bs[4096 + c0 * 8]);
    gload16(Bp1 + 32, &Bs[4096 + c1 * 8]);
    int cur = 0, nx2 = 2;
#pragma unroll 1
    for (int ks = 0; ks < 15; ++ks) {
        asm volatile("s_waitcnt vmcnt(4)" ::: "memory");
        __builtin_amdgcn_s_barrier();
        if (ks + 2 < 16) {
            const int kb = (ks + 2) * 32;
            const int nb = nx2 * 4096;
            gload16(Ap0 + kb, &As[nb + c0 * 8]);
            gload16(Ap1 + kb, &As[nb + c1 * 8]);
            gload16(Bp0 + kb, &Bs[nb + c0 * 8]);
            gload16(Bp1 + kb, &Bs[nb + c1 * 8]);
        }
        const int cb = cur * 4096;
        bf16x8 af[4], bfr[4];
#pragma unroll
        for (int i = 0; i < 4; ++i)
            af[i] = *(const bf16x8*)&As[cb + (wr + i * 16 + l16) * 32 + quad * 8];
#pragma unroll
        for (int j = 0; j < 4; ++j)
            bfr[j] = *(const bf16x8*)&Bs[cb + (wc + j * 16 + l16) * 32 + quad * 8];
#pragma unroll
        for (int i = 0; i < 4; ++i)
#pragma unroll
            for (int j = 0; j < 4; ++j)
                acc[i][j] = __builtin_amdgcn_mfma_f32_16x16x32_bf16(af[i], bfr[j], acc[i][j], 0, 0, 0);
        cur = (cur == 2) ? 0 : cur + 1;
        nx2 = (nx2 == 2) ? 0 : nx2 + 1;
    }
    {   // peeled last step
        asm volatile("s_waitcnt vmcnt(0)" ::: "memory");
        __builtin_amdgcn_s_barrier();
        const int cb = cur * 4096;
        bf16x8 af[4], bfr[4];
#pragma unroll
        for (int i = 0; i < 4; ++i)
            af[i] = *(const bf16x8*)&As[cb + (wr + i * 16 + l16) * 32 + quad * 8];
#pragma unroll
        for (int j = 0; j < 4; ++j)
            bfr[j] = *(const bf16x8*)&Bs[cb + (wc + j * 16 + l16) * 32 + quad * 8];
#pragma unroll
        for (int i = 0; i < 4; ++i)
#pragma unroll
            for (int j = 0; j < 4; ++j)
                acc[i][j] = __builtin_amdgcn_mfma_f32_16x16x32_bf16(af[i], bfr[j], acc[i][j], 0, 0, 0);
    }
#pragma unroll
    for (int i = 0; i < 4; ++i) {
        int rbase = row0 + wr + i * 16 + quad * 4;
#pragma unroll
        for (int j = 0; j < 4; ++j) {
            int c = col0 + wc + j * 16 + l16;
            int sec = c >> 9;           // uniform within a 64-col wave tile
            int cc = c & 511;
            float bv = bias[c];
#pragma unroll
            for (int rg = 0; rg < 4; ++rg) {
                int gr = rbase + rg;
                if (gr < M) {
                    float v = acc[i][j][rg] + bv;
                    if (sec == 1 || sec == 2) {
                        int r8 = __builtin_amdgcn_cvt_pk_fp8_f32(v, v, 0, false);
                        int off = (sec == 1) ? cc : 512 + cc;
                        kv8[(size_t)gr * 1024 + off] = (unsigned char)(r8 & 0xFF);
                    } else {
                        int off = (sec == 0) ? cc : 512 + cc;
                        qvs[(size_t)gr * 1024 + off] = (short)f2bf1(v);
                    }
                }
            }
        }
    }
}

// ---------------- fused gate GEMM v5: + pairscore fusion + final combine -------------
// 128 pairs x 512 cols per block, 512 thr (2Mx4N waves), acc[4][8] (AGPRs).
// Counted s_waitcnt keeps staged loads in flight across raw s_barriers (T3/T4).
// NO setprio (m190/R6). Pairscore fused (R12): bf16 gathers of tB[i]/zB[j] on the
// same channel schedule, dot hidden under the latency-bound structure. vmcnt audit:
// MU wait 6 (retires {Bmu,xn,yn}); AB wait 6 (retires {Bab,tn,zn}). Tail 4/0.

__global__ __launch_bounds__(512, 2) void gemm_gate(
    const unsigned char* __restrict__ z8,   // [Nn][1024] fp8
    const int* __restrict__ pi, const int* __restrict__ pj, int P,
    const short* __restrict__ Bt,    // gW1^T [512][2048], pre-swizzled
    const float* __restrict__ gb1,
    const float* __restrict__ gW2,
    const float* __restrict__ gb2,
    const short* __restrict__ tB,    // bilinear outputs [Nn][1024] bf16 (syn|ant)
    const short* __restrict__ zB,    // z [Nn][1024] bf16 (syn|ant)
    float* __restrict__ out) {
    __shared__ __align__(16) short Bab[2 * 512 * 32];   // 64 KB
    __shared__ __align__(16) short Bmu[2 * 512 * 32];   // 64 KB
    __shared__ __align__(16) short Asab[128 * 32];      // 8 KB
    __shared__ __align__(16) short Asmu[128 * 32];      // 8 KB
    __shared__ int iArr[128];
    __shared__ int jArr[128];
    __shared__ float rowsum[128];
    __shared__ float dsS[128];
    __shared__ float daS[128];
    const int row0 = blockIdx.x * 128;
    const int tid = threadIdx.x;
    const int lane = tid & 63;
    const int wave = tid >> 6;       // 0..7
    const int wm = wave >> 2;        // 0..1 : 64-row group
    const int wn = wave & 3;         // 0..3 : 128-col group
    const int l16 = lane & 15;
    const int quad = lane >> 4;
    const int arow = tid >> 2;       // 0..127
    const int aslot = tid & 3;
    const int qs = (quad ^ ((l16 >> 1) & 3)) * 8;                       // read swizzle
    const int awoff = arow * 32 + ((aslot ^ ((arow >> 1) & 3)) << 3);   // write swizzle

    if (tid < 128) {
        int p = row0 + tid;
        int ok = (p < P);
        iArr[tid] = ok ? pi[p] : 0;
        jArr[tid] = ok ? pj[p] : 0;
        rowsum[tid] = 0.0f;
    }
    __syncthreads();
    const unsigned char* zi = z8 + (size_t)iArr[arow] * 1024 + aslot * 8;
    const unsigned char* zj = z8 + (size_t)jArr[arow] * 1024 + aslot * 8;
    const short* tbi = tB + (size_t)iArr[arow] * 1024 + aslot * 8;
    const short* zbj = zB + (size_t)jArr[arow] * 1024 + aslot * 8;
    const short* brow = Bt + (size_t)(tid >> 2) * 2048 + (tid & 3) * 8;

    f32x4 acc[4][8];
#pragma unroll
    for (int i = 0; i < 4; ++i)
#pragma unroll
        for (int j = 0; j < 8; ++j)
            acc[i][j] = f32x4{0.f, 0.f, 0.f, 0.f};

    // B source offset (shorts) for k-chunk kc: part = kc>>4, chan = (kc&15)*32
    auto CHB = [](int kc) { return ((kc >> 4) << 10) + ((kc & 15) << 5); };
    // z/t channel offset for k-chunk kc (bytes for z8; shorts for bf16 — same number)
    auto KOFF = [](int kc) { return ((kc >> 4) << 9) + ((kc & 15) << 5); };
    auto STAGE = [&](int kc, int mu, short* buf) {
        const short* src = brow + CHB(kc) + (mu ? 512 : 0);
#pragma unroll
        for (int g = 0; g < 4; ++g)
            gload16(src + (size_t)(g * 128) * 2048, buf + (g * 512 + tid) * 8);
    };
    auto CVT = [&](uint2 xu, uint2 yu, uint4& aa, uint4& am) {
        f32x2 x0 = __builtin_amdgcn_cvt_pk_f32_fp8((int)xu.x, false);
        f32x2 x1 = __builtin_amdgcn_cvt_pk_f32_fp8((int)xu.x, true);
        f32x2 x2 = __builtin_amdgcn_cvt_pk_f32_fp8((int)xu.y, false);
        f32x2 x3 = __builtin_amdgcn_cvt_pk_f32_fp8((int)xu.y, true);
        f32x2 y0 = __builtin_amdgcn_cvt_pk_f32_fp8((int)yu.x, false);
        f32x2 y1 = __builtin_amdgcn_cvt_pk_f32_fp8((int)yu.x, true);
        f32x2 y2 = __builtin_amdgcn_cvt_pk_f32_fp8((int)yu.y, false);
        f32x2 y3 = __builtin_amdgcn_cvt_pk_f32_fp8((int)yu.y, true);
        aa.x = cvt_pk_bf16(fabsf(x0.x - y0.x), fabsf(x0.y - y0.y));
        aa.y = cvt_pk_bf16(fabsf(x1.x - y1.x), fabsf(x1.y - y1.y));
        aa.z = cvt_pk_bf16(fabsf(x2.x - y2.x), fabsf(x2.y - y2.y));
        aa.w = cvt_pk_bf16(fabsf(x3.x - y3.x), fabsf(x3.y - y3.y));
        am.x = cvt_pk_bf16(x0.x * y0.x, x0.y * y0.y);
        am.y = cvt_pk_bf16(x1.x * y1.x, x1.y * y1.y);
        am.z = cvt_pk_bf16(x2.x * y2.x, x2.y * y2.y);
        am.w = cvt_pk_bf16(x3.x * y3.x, x3.y * y3.y);
    };
    auto DOT8 = [&](uint4 tv, uint4 zv) -> float {
        float2 t0 = bfp2(tv.x), t1 = bfp2(tv.y), t2 = bfp2(tv.z), t3 = bfp2(tv.w);
        float2 p0 = bfp2(zv.x), p1 = bfp2(zv.y), p2 = bfp2(zv.z), p3 = bfp2(zv.w);
        return t0.x * p0.x + t0.y * p0.y + t1.x * p1.x + t1.y * p1.y +
               t2.x * p2.x + t2.y * p2.y + t3.x * p3.x + t3.y * p3.y;
    };
    auto MFMA_PHASE = [&](const short* As, const short* Bp) {
        bf16x8 af[4];
#pragma unroll
        for (int i = 0; i < 4; ++i)
            af[i] = *(const bf16x8*)&As[(wm * 64 + i * 16 + l16) * 32 + qs];
#pragma unroll
        for (int j = 0; j < 8; ++j) {
            bf16x8 bf = *(const bf16x8*)&Bp[(wn * 128 + j * 16 + l16) * 32 + qs];
#pragma unroll
            for (int i = 0; i < 4; ++i)
                acc[i][j] = __builtin_amdgcn_mfma_f32_16x16x32_bf16(af[i], bf, acc[i][j], 0, 0, 0);
        }
    };

    // ---- prologue: stage AB(0), load z(0) + t/z-bf16(0), cvt ----
    STAGE(0, 0, Bab);
    uint2 xu = *(const uint2*)zi;
    uint2 yu = *(const uint2*)zj;
    uint4 tu = *(const uint4*)tbi;      // chunk 0
    uint4 zu = *(const uint4*)zbj;
    uint4 aa, am, am_hold;
    CVT(xu, yu, aa, am);
    *(uint4*)&Asab[awoff] = aa;
    am_hold = am;
    float ds = 0.f, da = 0.f;

#pragma unroll 1
    for (int kc = 0; kc < 31; ++kc) {
        const int cur = kc & 1;
        // ---- AB sub-phase ----
        STAGE(kc, 1, Bmu + cur * 16384);
        uint2 xn = *(const uint2*)(zi + KOFF(kc + 1));
        uint2 yn = *(const uint2*)(zj + KOFF(kc + 1));
        {   // pairscore dot for chunk kc (tu,zu loaded last MU / prologue)
            float pd = DOT8(tu, zu);
            if (kc < 16) ds += pd; else da += pd;
        }
        asm volatile("s_waitcnt vmcnt(6) lgkmcnt(0)" ::: "memory");
        __builtin_amdgcn_s_barrier();
        MFMA_PHASE(Asab, Bab + cur * 16384);
        *(uint4*)&Asmu[awoff] = am_hold;          // post-section write (for mu of this kc)
        // ---- MU sub-phase ----
        STAGE(kc + 1, 0, Bab + (cur ^ 1) * 16384);
        tu = *(const uint4*)(tbi + KOFF(kc + 1));  // chunk kc+1
        zu = *(const uint4*)(zbj + KOFF(kc + 1));
        CVT(xn, yn, aa, am);                      // implicit z-wait retires Bmu[cur]
        asm volatile("s_waitcnt vmcnt(6) lgkmcnt(0)" ::: "memory");
        __builtin_amdgcn_s_barrier();
        MFMA_PHASE(Asmu, Bmu + cur * 16384);
        *(uint4*)&Asab[awoff] = aa;               // post-section write (for ab of kc+1)
        am_hold = am;
    }
    // ---- tail kc = 31 (cur = 1) ----
    STAGE(31, 1, Bmu + 16384);
    da += DOT8(tu, zu);                           // chunk 31 (ant half)
    asm volatile("s_waitcnt vmcnt(4) lgkmcnt(0)" ::: "memory");
    __builtin_amdgcn_s_barrier();
    MFMA_PHASE(Asab, Bab + 16384);
    *(uint4*)&Asmu[awoff] = am_hold;
    asm volatile("s_waitcnt vmcnt(0) lgkmcnt(0)" ::: "memory");
    __builtin_amdgcn_s_barrier();
    MFMA_PHASE(Asmu, Bmu + 16384);

    // ---- pairscore reduce across the 4 aslot lanes of each row ----
    ds += __shfl_xor(ds, 1);
    ds += __shfl_xor(ds, 2);
    da += __shfl_xor(da, 1);
    da += __shfl_xor(da, 2);
    if (aslot == 0) { dsS[arow] = ds; daS[arow] = da; }

    // ---- epilogue: fused gelu + gW2 dot, per-row reduce, sigmoid combine ----
#pragma unroll
    for (int i = 0; i < 4; ++i) {
#pragma unroll
        for (int rg = 0; rg < 4; ++rg) {
            float partial = 0.f;
#pragma unroll
            for (int j = 0; j < 8; ++j) {
                int cc = wn * 128 + j * 16 + l16;
                partial += gelu1(acc[i][j][rg] + gb1[cc]) * gW2[cc];
            }
            partial += __shfl_xor(partial, 1);
            partial += __shfl_xor(partial, 2);
            partial += __shfl_xor(partial, 4);
            partial += __shfl_xor(partial, 8);
            if (l16 == 0)
                atomicAdd(&rowsum[wm * 64 + i * 16 + quad * 4 + rg], partial);
        }
    }
    __syncthreads();
    if (tid < 128) {
        int p = row0 + tid;
        if (p < P) {
            float s = 1.0f / (1.0f + __expf(-(rowsum[tid] + gb2[0])));
            out[p] = s * daS[tid] - (1.0f - s) * dsS[tid];
        }
    }
}

// ---------------- fused per-layer attention: single-pass, fp8 k AND v gather ----------
// qvs bf16 [Nn][1024] (q|s), kv8 fp8 [Nn][1024] (k|v). Per edge: 8B k + 8B v per lane.
// Edge loop unrolled 8-deep (R7/R11): scattered kv8 loads issued up front for MLP;
// sequential online-softmax order preserved (numerics identical).
// R13: `last` flag skips the f32 h write on the final layer (dead store — only h_bf
// is consumed downstream by the dual GEMM). Saves 40 MB of HBM writes.

__global__ __launch_bounds__(256) void k_attn(const short* __restrict__ qvs,
                                              const unsigned char* __restrict__ kv8,
                                              const int* __restrict__ srcS,
                                              const int* __restrict__ offs,
                                              float* __restrict__ h,
                                              short* __restrict__ h_bf,
                                              const float* __restrict__ lng,
                                              const float* __restrict__ lnb, int Nn,
                                              int last) {
    const int tid = threadIdx.x;
    const int lane = tid & 63;
    const int wv = tid >> 6;
    const int n = blockIdx.x * 4 + wv;
    if (n >= Nn) return;
    const int st = offs[n], en = offs[n + 1];
    const size_t chOff = (size_t)lane * 8;

    uint4 qv = *(const uint4*)(qvs + (size_t)n * 1024 + chOff);
    float2 q0 = bfp2(qv.x), q1 = bfp2(qv.y), q2 = bfp2(qv.z), q3 = bfp2(qv.w);
    float acc[8];
#pragma unroll
    for (int i = 0; i < 8; ++i) acc[i] = 0.f;
    float m_l = -3.4e38f, l_l = 0.f;

    auto PROC = [&](uint2 kq, uint2 vq) {
        f32x2 k0 = __builtin_amdgcn_cvt_pk_f32_fp8((int)kq.x, false);
        f32x2 k1 = __builtin_amdgcn_cvt_pk_f32_fp8((int)kq.x, true);
        f32x2 k2 = __builtin_amdgcn_cvt_pk_f32_fp8((int)kq.y, false);
        f32x2 k3 = __builtin_amdgcn_cvt_pk_f32_fp8((int)kq.y, true);
        float d = q0.x * k0.x + q0.y * k0.y + q1.x * k1.x + q1.y * k1.y +
                  q2.x * k2.x + q2.y * k2.y + q3.x * k3.x + q3.y * k3.y;
        d += __shfl_xor(d, 1);
        d += __shfl_xor(d, 2);
        d += __shfl_xor(d, 4);
        d += __shfl_xor(d, 8);
        float lg = d * 0.08838834764831845f;
        float m_new = fmaxf(m_l, lg);
        float sc = __expf(m_l - m_new);
        float p = __expf(lg - m_new);
        l_l = l_l * sc + p;
        m_l = m_new;
        f32x2 v0 = __builtin_amdgcn_cvt_pk_f32_fp8((int)vq.x, false);
        f32x2 v1 = __builtin_amdgcn_cvt_pk_f32_fp8((int)vq.x, true);
        f32x2 v2 = __builtin_amdgcn_cvt_pk_f32_fp8((int)vq.y, false);
        f32x2 v3 = __builtin_amdgcn_cvt_pk_f32_fp8((int)vq.y, true);
        acc[0] = acc[0] * sc + p * v0.x; acc[1] = acc[1] * sc + p * v0.y;
        acc[2] = acc[2] * sc + p * v1.x; acc[3] = acc[3] * sc + p * v1.y;
        acc[4] = acc[4] * sc + p * v2.x; acc[5] = acc[5] * sc + p * v2.y;
        acc[6] = acc[6] * sc + p * v3.x; acc[7] = acc[7] * sc + p * v3.y;
    };

    for (int e0 = st; e0 < en; e0 += 64) {
        int cnt = min(64, en - e0);
        int myS = (lane < cnt) ? srcS[e0 + lane] : 0;
        int ei = 0;
        for (; ei + 8 <= cnt; ei += 8) {
            const unsigned char* rp[8];
#pragma unroll
            for (int u = 0; u < 8; ++u) {
                int s = __shfl(myS, ei + u);
                rp[u] = kv8 + (size_t)s * 1024 + chOff;
            }
            uint2 kk[8], vv[8];
#pragma unroll
            for (int u = 0; u < 8; ++u) {
                kk[u] = *(const uint2*)rp[u];
                vv[u] = *(const uint2*)(rp[u] + 512);
            }
#pragma unroll
            for (int u = 0; u < 8; ++u) PROC(kk[u], vv[u]);
        }
        for (; ei < cnt; ++ei) {
            int s = __shfl(myS, ei);
            const unsigned char* srow = kv8 + (size_t)s * 1024 + chOff;
            uint2 kq = *(const uint2*)srow;
            uint2 vq = *(const uint2*)(srow + 512);
            PROC(kq, vq);
        }
    }
    float rinv = (en > st) ? 1.0f / l_l : 0.f;
    uint4 su = *(const uint4*)(qvs + (size_t)n * 1024 + 512 + chOff);
    float2 s0 = bfp2(su.x), s1 = bfp2(su.y), s2 = bfp2(su.z), s3 = bfp2(su.w);
    float sv[8] = {s0.x, s0.y, s1.x, s1.y, s2.x, s2.y, s3.x, s3.y};
    const float* hp = h + (size_t)n * 512 + chOff;
    float4 h0 = *(const float4*)hp;
    float4 h1 = *(const float4*)(hp + 4);
    float hv[8] = {h0.x, h0.y, h0.z, h0.w, h1.x, h1.y, h1.z, h1.w};
    float r[8];
    float sum = 0.f, ssq = 0.f;
#pragma unroll
    for (int i = 0; i < 8; ++i) {
        r[i] = hv[i] + gelu1(acc[i] * rinv + sv[i]);
        sum += r[i];
        ssq += r[i] * r[i];
    }
    for (int o = 32; o; o >>= 1) {
        sum += __shfl_xor(sum, o);
        ssq += __shfl_xor(ssq, o);
    }
    float mean = sum * (1.0f / 512.0f);
    float var = ssq * (1.0f / 512.0f) - mean * mean;
    float inv = rsqrtf(var + 1e-5f);
    const float* gp = lng + chOff;
    const float* bp = lnb + chOff;
    float4 g0 = *(const float4*)gp, g1 = *(const float4*)(gp + 4);
    float4 b0 = *(const float4*)bp, b1 = *(const float4*)(bp + 4);
    float ga[8] = {g0.x, g0.y, g0.z, g0.w, g1.x, g1.y, g1.z, g1.w};
    float ba[8] = {b0.x, b0.y, b0.z, b0.w, b1.x, b1.y, b1.z, b1.w};
    float o8[8];
#pragma unroll
    for (int i = 0; i < 8; ++i) o8[i] = (r[i] - mean) * inv * ga[i] + ba[i];
    if (!last) {
        float* hw = h + (size_t)n * 512 + chOff;
        *(float4*)hw = make_float4(o8[0], o8[1], o8[2], o8[3]);
        *(float4*)(hw + 4) = make_float4(o8[4], o8[5], o8[6], o8[7]);
    }
    uint4 ob;
    ob.x = f2bf2(o8[0], o8[1]);
    ob.y = f2bf2(o8[2], o8[3]);
    ob.z = f2bf2(o8[4], o8[5]);
    ob.w = f2bf2(o8[6], o8[7]);
    *(uint4*)(h_bf + (size_t)n * 512 + chOff) = ob;
}

// ---------------- host ----------------

extern "C" void kernel_launch(void* const* d_in, const int* in_sizes, int n_in,
                              void* d_out, int out_size, void* d_ws, size_t ws_size,
                              hipStream_t stream) {
    const float* x = (const float*)d_in[0];
    const int* ei = (const int*)d_in[1];
    const int* pe = (const int*)d_in[2];
    const float* mixer_W = (const float*)d_in[3];
    const float* mixer_b = (const float*)d_in[4];
    const float* Wq = (const float*)d_in[5];
    const float* bq = (const float*)d_in[6];
    const float* Wk = (const float*)d_in[7];
    const float* bk = (const float*)d_in[8];
    const float* Wv = (const float*)d_in[9];
    const float* bv = (const float*)d_in[10];
    const float* Ws = (const float*)d_in[11];
    const float* bs = (const float*)d_in[12];
    const float* ln_g = (const float*)d_in[13];
    const float* ln_b = (const float*)d_in[14];
    const float* syn_W = (const float*)d_in[15];
    const float* syn_b = (const float*)d_in[16];
    const float* ant_W = (const float*)d_in[17];
    const float* ant_b = (const float*)d_in[18];
    const float* W_syn = (const float*)d_in[19];
    const float* W_ant = (const float*)d_in[20];
    const float* gW1 = (const float*)d_in[21];
    const float* gb1 = (const float*)d_in[22];
    const float* gW2 = (const float*)d_in[23];
    const float* gb2 = (const float*)d_in[24];
    float* out = (float*)d_out;

    const int Nn = in_sizes[0] / 768;  // 20000
    const int E = in_sizes[1] / 2;     // 320000
    const int P = in_sizes[2] / 2;     // 100000

    char* w = (char*)d_ws;
    auto alloc = [&](size_t bytes) -> char* {
        char* p = w;
        w += (bytes + 255) & ~(size_t)255;
        return p;
    };
    float* h = (float*)alloc((size_t)Nn * 512 * 4);
    short* h_bf = (short*)alloc((size_t)Nn * 512 * 2);
    // union region U: pre-mixer = x_bf [Nn][768] bf16 ; during layers = qvs [Nn][1024]
    // bf16 (q|s) + kv8 [Nn][1024] fp8 (k|v) ; after layers = zB | tB (bf16)
    char* U = alloc((size_t)Nn * 2048 * 2);
    short* x_bf = (short*)U;                      // 30.7 MB < |U|; dead after mixer
    short* qvs = (short*)U;
    unsigned char* kv8 = (unsigned char*)(U + (size_t)Nn * 1024 * 2);
    short* zB = (short*)U;
    short* tB = (short*)(U + (size_t)Nn * 1024 * 2);
    unsigned char* z8 = (unsigned char*)alloc((size_t)Nn * 1024);   // fp8 z copy, 20 MB
    int* srcS = (int*)alloc((size_t)E * 4);
    int* hist = (int*)alloc((size_t)Nn * 2 * 4);
    int* cursor = hist + Nn;
    int* offs = (int*)alloc((size_t)(Nn + 1) * 4);
    short* mixWt = (short*)alloc((size_t)512 * 768 * 2);
    short* wcat = (short*)alloc((size_t)L_LAYERS * 2048 * 512 * 2);
    short* dualWt = (short*)alloc((size_t)1024 * 512 * 2);
    short* bilWt = (short*)alloc((size_t)1024 * 512 * 2);
    short* gw1t = (short*)alloc((size_t)512 * 2048 * 2);
    float* bcat = (float*)alloc((size_t)L_LAYERS * 2048 * 4);
    float* bdual = (float*)alloc((size_t)1024 * 4);

    k_zero<<<(2 * Nn + 255) / 256, 256, 0, stream>>>(hist, 2 * Nn);
    k_hist<<<(E + 255) / 256, 256, 0, stream>>>(ei + E, hist, E);
    k_scan<<<1, 1024, 0, stream>>>(hist, offs, Nn);
    k_scatter<<<(E + 255) / 256, 256, 0, stream>>>(ei, ei + E, offs, cursor, srcS, E);

    k_wcat<<<(L_LAYERS * 2048 * 512) / 256, 256, 0, stream>>>(Wq, Wk, Wv, Ws, wcat);
    k_tr<<<dim3(3, 512), 256, 0, stream>>>(mixer_W, mixWt, 768, 512, 0);
    k_tr<<<dim3(2, 512), 256, 0, stream>>>(syn_W, dualWt, 512, 512, 0);
    k_tr<<<dim3(2, 512), 256, 0, stream>>>(ant_W, dualWt + 512 * 512, 512, 512, 0);
    k_tr<<<dim3(2, 512), 256, 0, stream>>>(W_syn, bilWt, 512, 512, 0);
    k_tr<<<dim3(2, 512), 256, 0, stream>>>(W_ant, bilWt + 512 * 512, 512, 512, 0);
    k_tr<<<dim3(8, 512), 256, 0, stream>>>(gW1, gw1t, 2048, 512, 1);   // pre-swizzled for gemm_gate
    k_bcat<<<48, 256, 0, stream>>>(bq, bk, bv, bs, bcat);
    k_bdual<<<4, 256, 0, stream>>>(syn_b, ant_b, bdual);

    const int mtiles = (Nn + 127) / 128;  // 157
    // mixer: x -> bf16 once, then gload_lds GEMM (replaces VALU-bound gemm_a32)
    k_cvt<<<(Nn * 768 / 8 + 255) / 256, 256, 0, stream>>>(x, x_bf, Nn * 768 / 8);
    gemm_bb<<<dim3(mtiles, 4), 256, 0, stream>>>(x_bf, 768, mixWt, mixer_b, h_bf,
                                                 nullptr, h, 512, Nn, 512, 768, 1, 0);

    // XCD-swizzled 1D grid: ceil(mtiles/8)*8 row slots x 16 col tiles
    const int qk_grid = ((mtiles + 7) / 8) * 8 * 16;   // 2560
    for (int l = 0; l < L_LAYERS; ++l) {
        gemm_qkvs<<<qk_grid, 256, 0, stream>>>(h_bf, wcat + (size_t)l * 2048 * 512,
                                               bcat + l * 2048, qvs, kv8, Nn, mtiles);
        k_attn<<<(Nn + 3) / 4, 256, 0, stream>>>(qvs, kv8, srcS, offs, h, h_bf,
                                                 ln_g + l * 512, ln_b + l * 512, Nn,
                                                 l == L_LAYERS - 1 ? 1 : 0);
    }

    // z = gelu(h @ [syn_W|ant_W] + b) -> zB bf16 + z8 fp8
    gemm_bb<<<dim3(mtiles, 8), 256, 0, stream>>>(h_bf, 512, dualWt, bdual, zB, z8,
                                                 nullptr, 1024, Nn, 1024, 512, 1, 0);
    // merged bilinear: tB[:,0:512] = zB[:,0:512]@W_syn^T ; tB[:,512:] = zB[:,512:]@W_ant^T
    gemm_bb<<<dim3(mtiles, 8), 256, 0, stream>>>(zB, 1024, bilWt, nullptr, tB, nullptr,
                                                 nullptr, 1024, Nn, 1024, 512, 0, 1);

    // gate + pairscore + final combine, all fused
    const int ptiles2 = (P + 127) / 128;               // 782
    gemm_gate<<<ptiles2, 512, 0, stream>>>(z8, pe, pe + P, P, gw1t, gb1, gW2,
                                           gb2, tB, zB, out);
}